// Round 15
// baseline (179.296 us; speedup 1.0000x reference)
//
#include <hip/hip_runtime.h>
#include <math.h>

// Match XLA/LAPACK f32 rounding: no FMA contraction anywhere in this file.
#pragma clang fp contract(off)

#define NPTS 4096
#define NBATCH 4
#define NTOT (NBATCH * NPTS)
#define NNB 20
#define NBINS 5
#define LTOP 7    // per-lane top-list size; P(lane holds >=8 of top-20) ~ 5e-4 total
#define WST 8     // shot threads per block (8 active lanes/wave -> 2048 waves = 2/SIMD)

// f32 LAPACK machine constants
#define SEPS    5.9604644775390625e-8f   // SLAMCH('E') = 2^-24
#define SSAFMIN 1.17549435e-38f          // SLAMCH('S') = 2^-126

// ---------------- LAPACK helpers (f32, faithful to reference LAPACK >= 3.10) ----------------

__device__ __forceinline__ float f_signf(float a, float b) {
  return __builtin_signbit(b) ? -fabsf(a) : fabsf(a);
}

__device__ float slapy2_(float x, float y) {
  float xa = fabsf(x), ya = fabsf(y);
  float w = fmaxf(xa, ya), z = fminf(xa, ya);
  if (z == 0.0f) return w;
  float t = z / w;
  return w * sqrtf(1.0f + t * t);
}

// LAPACK >= 3.10 slartg (c = |f|/d >= 0, r = sign(f)*d); unscaled path (values are moderate)
__device__ void slartg_(float f, float g, float* c, float* s, float* r) {
  if (g == 0.0f) {
    *c = 1.0f; *s = 0.0f; *r = f;
  } else if (f == 0.0f) {
    *c = 0.0f; *s = __builtin_signbit(g) ? -1.0f : 1.0f; *r = fabsf(g);
  } else {
    float f1 = fabsf(f);
    float d = sqrtf(f * f + g * g);
    *c = f1 / d;
    float rr = __builtin_signbit(f) ? -d : d;
    *r = rr;
    *s = g / rr;
  }
}

__device__ void slaev2_(float a, float b, float c,
                        float* rt1, float* rt2, float* cs1, float* sn1) {
  float sm = a + c;
  float df = a - c;
  float adf = fabsf(df);
  float tb = b + b;
  float ab = fabsf(tb);
  float acmx, acmn;
  if (fabsf(a) > fabsf(c)) { acmx = a; acmn = c; } else { acmx = c; acmn = a; }
  float rt;
  if (adf > ab)      { float t = ab / adf; rt = adf * sqrtf(1.0f + t * t); }
  else if (adf < ab) { float t = adf / ab; rt = ab * sqrtf(1.0f + t * t); }
  else               { rt = ab * sqrtf(2.0f); }
  int sgn1;
  if (sm < 0.0f) {
    *rt1 = 0.5f * (sm - rt); sgn1 = -1;
    *rt2 = (acmx / *rt1) * acmn - (b / *rt1) * b;
  } else if (sm > 0.0f) {
    *rt1 = 0.5f * (sm + rt); sgn1 = 1;
    *rt2 = (acmx / *rt1) * acmn - (b / *rt1) * b;
  } else {
    *rt1 = 0.5f * rt; *rt2 = -0.5f * rt; sgn1 = 1;
  }
  float cs; int sgn2;
  if (df >= 0.0f) { cs = df + rt; sgn2 = 1; }
  else            { cs = df - rt; sgn2 = -1; }
  float acs = fabsf(cs);
  float csv, snv;
  if (acs > ab) {
    float ct = -tb / cs;
    snv = 1.0f / sqrtf(1.0f + ct * ct);
    csv = ct * snv;
  } else {
    if (ab == 0.0f) { csv = 1.0f; snv = 0.0f; }
    else {
      float tn = -cs / tb;
      csv = 1.0f / sqrtf(1.0f + tn * tn);
      snv = tn * csv;
    }
  }
  if (sgn1 == sgn2) { float tn = csv; csv = -snv; snv = tn; }
  *cs1 = csv; *sn1 = snv;
}

// Per-lane LDS workspace accessors: element i of this lane lives at w[i*WST].
// Layout: d[0..2]=0..2, e[0..1]=3..4, Z[i][j]=5+i*3+j, wc[0..1]=14..15, wsn[0..1]=16..17.
#define DD(i)    w[(i) * WST]
#define EE(i)    w[(3 + (i)) * WST]
#define ZZ(i, j) w[(5 + (i) * 3 + (j)) * WST]
#define CC(i)    w[(14 + (i)) * WST]
#define SN(i)    w[(16 + (i)) * WST]

// SSTEQR('I', n=3) faithful port; arrays in LDS (runtime-indexed -> scratch otherwise)
__device__ void ssteqr3_lds(float* w) {
  const int n = 3;
  const float eps = SEPS;
  const float eps2 = SEPS * SEPS;
  const float safmin = SSAFMIN;
  const int nmaxit = 90;
  int jtot = 0;
  int l1 = 1;
  int l = 0, lsv = 0, lend = 0, lendsv = 0, m = 0, mm = 0;
  float p = 0, g = 0, r = 0, c = 0, s = 0, f = 0, bb = 0, rt1 = 0, rt2 = 0;
  float anorm = 0, tst = 0;

L10:
  if (l1 > n) goto L160;
  if (l1 > 1) EE(l1 - 2) = 0.0f;
  if (l1 <= n - 1) {
    for (m = l1; m <= n - 1; ++m) {
      tst = fabsf(EE(m - 1));
      if (tst == 0.0f) goto L30;
      if (tst <= (sqrtf(fabsf(DD(m - 1))) * sqrtf(fabsf(DD(m)))) * eps) {
        EE(m - 1) = 0.0f;
        goto L30;
      }
    }
  }
  m = n;
L30:
  l = l1; lsv = l; lend = m; lendsv = lend; l1 = m + 1;
  if (lend == l) goto L10;
  anorm = 0.0f;
  for (int i = l; i <= lend; ++i) anorm = fmaxf(anorm, fabsf(DD(i - 1)));
  for (int i = l; i <= lend - 1; ++i) anorm = fmaxf(anorm, fabsf(EE(i - 1)));
  if (anorm == 0.0f) goto L10;
  if (fabsf(DD(lend - 1)) < fabsf(DD(l - 1))) { lend = lsv; l = lendsv; }

  if (lend > l) {
L40:
    if (l != lend) {
      for (m = l; m <= lend - 1; ++m) {
        tst = EE(m - 1) * EE(m - 1);
        if (tst <= (eps2 * fabsf(DD(m - 1))) * fabsf(DD(m)) + safmin) goto L60;
      }
    }
    m = lend;
L60:
    if (m < lend) EE(m - 1) = 0.0f;
    p = DD(l - 1);
    if (m == l) goto L80;
    if (m == l + 1) {
      slaev2_(DD(l - 1), EE(l - 1), DD(l), &rt1, &rt2, &c, &s);
      for (int i = 0; i < n; ++i) {
        float tz = ZZ(i, l);
        ZZ(i, l)     = c * tz - s * ZZ(i, l - 1);
        ZZ(i, l - 1) = s * tz + c * ZZ(i, l - 1);
      }
      DD(l - 1) = rt1; DD(l) = rt2; EE(l - 1) = 0.0f;
      l += 2;
      if (l <= lend) goto L40;
      goto L140;
    }
    if (jtot == nmaxit) goto L140;
    jtot++;
    g = (DD(l) - p) / (2.0f * EE(l - 1));
    r = slapy2_(g, 1.0f);
    g = DD(m - 1) - p + EE(l - 1) / (g + f_signf(r, g));
    s = 1.0f; c = 1.0f; p = 0.0f;
    for (int i = m - 1; i >= l; --i) {
      f = s * EE(i - 1);
      bb = c * EE(i - 1);
      slartg_(g, f, &c, &s, &r);
      if (i != m - 1) EE(i) = r;
      g = DD(i) - p;
      r = (DD(i - 1) - g) * s + 2.0f * c * bb;
      p = s * r;
      DD(i) = g + p;
      g = c * r - bb;
      CC(i - 1) = c; SN(i - 1) = -s;
    }
    mm = m - l + 1;
    for (int j = mm - 1; j >= 1; --j) {
      float ct = CC(l + j - 2), st = SN(l + j - 2);
      for (int i = 0; i < n; ++i) {
        float tz = ZZ(i, l + j - 1);
        ZZ(i, l + j - 1) = ct * tz - st * ZZ(i, l + j - 2);
        ZZ(i, l + j - 2) = st * tz + ct * ZZ(i, l + j - 2);
      }
    }
    DD(l - 1) -= p;
    EE(l - 1) = g;
    goto L40;
L80:
    DD(l - 1) = p;
    l++;
    if (l <= lend) goto L40;
    goto L140;
  } else {
L90:
    if (l != lend) {
      for (m = l; m >= lend + 1; --m) {
        tst = EE(m - 2) * EE(m - 2);
        if (tst <= (eps2 * fabsf(DD(m - 1))) * fabsf(DD(m - 2)) + safmin) goto L110;
      }
    }
    m = lend;
L110:
    if (m > lend) EE(m - 2) = 0.0f;
    p = DD(l - 1);
    if (m == l) goto L130;
    if (m == l - 1) {
      slaev2_(DD(l - 2), EE(l - 2), DD(l - 1), &rt1, &rt2, &c, &s);
      for (int i = 0; i < n; ++i) {
        float tz = ZZ(i, l - 1);
        ZZ(i, l - 1) = c * tz - s * ZZ(i, l - 2);
        ZZ(i, l - 2) = s * tz + c * ZZ(i, l - 2);
      }
      DD(l - 2) = rt1; DD(l - 1) = rt2; EE(l - 2) = 0.0f;
      l -= 2;
      if (l >= lend) goto L90;
      goto L140;
    }
    if (jtot == nmaxit) goto L140;
    jtot++;
    g = (DD(l - 2) - p) / (2.0f * EE(l - 2));
    r = slapy2_(g, 1.0f);
    g = DD(m - 1) - p + EE(l - 2) / (g + f_signf(r, g));
    s = 1.0f; c = 1.0f; p = 0.0f;
    for (int i = m; i <= l - 1; ++i) {
      f = s * EE(i - 1);
      bb = c * EE(i - 1);
      slartg_(g, f, &c, &s, &r);
      if (i != m) EE(i - 2) = r;
      g = DD(i - 1) - p;
      r = (DD(i) - g) * s + 2.0f * c * bb;
      p = s * r;
      DD(i - 1) = g + p;
      g = c * r - bb;
      CC(i - 1) = c; SN(i - 1) = s;
    }
    mm = l - m + 1;
    for (int j = 1; j <= mm - 1; ++j) {
      float ct = CC(m + j - 2), st = SN(m + j - 2);
      for (int i = 0; i < n; ++i) {
        float tz = ZZ(i, m + j - 1);
        ZZ(i, m + j - 1) = ct * tz - st * ZZ(i, m + j - 2);
        ZZ(i, m + j - 2) = st * tz + ct * ZZ(i, m + j - 2);
      }
    }
    DD(l - 1) -= p;
    EE(l - 2) = g;
    goto L90;
L130:
    DD(l - 1) = p;
    l--;
    if (l >= lend) goto L90;
    goto L140;
  }
L140:
  if (jtot < nmaxit) goto L10;
  goto L160;
L160:
  for (int ii = 2; ii <= n; ++ii) {
    int i = ii - 1, k = i;
    float pp = DD(i - 1);
    for (int j = ii; j <= n; ++j)
      if (DD(j - 1) < pp) { k = j; pp = DD(j - 1); }
    if (k != i) {
      DD(k - 1) = DD(i - 1); DD(i - 1) = pp;
      for (int row = 0; row < n; ++row) {
        float t2 = ZZ(row, i - 1); ZZ(row, i - 1) = ZZ(row, k - 1); ZZ(row, k - 1) = t2;
      }
    }
  }
}

// ssyevd('V','L') for 3x3: ssytd2 -> ssteqr('I') -> sormtr. Workspace in LDS (w = base+lane).
__device__ void eigh3f_lds(float A00, float A10, float A20, float A11, float A21, float A22,
                           float* w, float V[3][3]) {
  float taui, v2, beta;
  float alpha = A10;
  float xnorm = fabsf(A20);
  if (xnorm == 0.0f) {
    taui = 0.0f; beta = alpha; v2 = 0.0f;
  } else {
    beta = -f_signf(slapy2_(alpha, xnorm), alpha);
    taui = (beta - alpha) / beta;
    v2 = A20 * (1.0f / (alpha - beta));
  }
  float a11 = A11, a21 = A21, a22 = A22;
  if (taui != 0.0f) {
    float w0 = taui * (a11 + a21 * v2);
    float w1 = taui * (a21 + a22 * v2);
    float al = -0.5f * taui * (w0 + w1 * v2);
    w0 += al; w1 += al * v2;
    a11 -= 2.0f * w0;
    a21 -= (v2 * w0 + w1);
    a22 -= 2.0f * (v2 * w1);
  }
  DD(0) = A00; DD(1) = a11; DD(2) = a22;
  EE(0) = beta; EE(1) = a21;
  ZZ(0, 0) = 1.0f; ZZ(0, 1) = 0.0f; ZZ(0, 2) = 0.0f;
  ZZ(1, 0) = 0.0f; ZZ(1, 1) = 1.0f; ZZ(1, 2) = 0.0f;
  ZZ(2, 0) = 0.0f; ZZ(2, 1) = 0.0f; ZZ(2, 2) = 1.0f;

  ssteqr3_lds(w);

  for (int k = 0; k < 3; ++k) {
    float t = taui * (ZZ(1, k) + v2 * ZZ(2, k));
    ZZ(1, k) -= t;
    ZZ(2, k) -= t * v2;
  }
  for (int i = 0; i < 3; ++i)
    for (int k = 0; k < 3; ++k) V[i][k] = ZZ(i, k);
}

// wave64 u32 min-reduce via DPP (row_shr 1/2/4/8 + row_bcast15/31); result valid in lane 63.
__device__ __forceinline__ unsigned wave_min_dpp(unsigned v) {
  unsigned t;
  t = (unsigned)__builtin_amdgcn_update_dpp(-1, (int)v, 0x111, 0xf, 0xf, false); v = t < v ? t : v;
  t = (unsigned)__builtin_amdgcn_update_dpp(-1, (int)v, 0x112, 0xf, 0xf, false); v = t < v ? t : v;
  t = (unsigned)__builtin_amdgcn_update_dpp(-1, (int)v, 0x114, 0xf, 0xf, false); v = t < v ? t : v;
  t = (unsigned)__builtin_amdgcn_update_dpp(-1, (int)v, 0x118, 0xf, 0xf, false); v = t < v ? t : v;
  t = (unsigned)__builtin_amdgcn_update_dpp(-1, (int)v, 0x142, 0xa, 0xf, false); v = t < v ? t : v;
  t = (unsigned)__builtin_amdgcn_update_dpp(-1, (int)v, 0x143, 0xc, 0xf, false); v = t < v ? t : v;
  return v;
}

// ---------------- Kernel A: wave-per-point KNN (FROZEN at R12 best: 72.3 us) ----------------

__global__ __launch_bounds__(1024, 8) void knn_kernel(const float* __restrict__ coords,
                                                      float* __restrict__ nbrD,
                                                      int* __restrict__ nbrI,
                                                      float* __restrict__ d16) {
  __shared__ float4 scs[NPTS];     // 64 KB: {x, y, z, sq}
  int tid = threadIdx.x;
  int wid = tid >> 6;
  int lane = tid & 63;
  int P = blockIdx.x * 16 + wid;   // 16 | 4096, no batch crossing
  int b = P >> 12;
  int p = P & (NPTS - 1);
  const float* cb = coords + (size_t)b * NPTS * 3;

  for (int i = tid; i < NPTS; i += 1024) {
    float x = cb[3 * i + 0], y = cb[3 * i + 1], z = cb[3 * i + 2];
    float sq = (x * x + y * y) + z * z;   // exact ref expression order
    scs[i] = make_float4(x, y, z, sq);
  }
  __syncthreads();

  float4 ci = scs[p];
  float xi = ci.x, yi = ci.y, zi = ci.z, sqi = ci.w;

  const double INF = __hiloint2double(0x7FF00000, 0);   // +inf sentinel (> any composite)
  double L[LTOP];
#pragma unroll
  for (int t = 0; t < LTOP; ++t) L[t] = INF;

#pragma unroll 8
  for (int k = 0; k < NPTS / 64; ++k) {
    int j = k * 64 + lane;
    float4 cj = scs[j];                       // one ds_read_b128
    float dot = (xi * cj.x + yi * cj.y) + zi * cj.z;
    float d2 = (sqi - 2.0f * dot) + cj.w;     // exact ref expression order
    unsigned kb = __float_as_uint(d2) & 0x7FFFFFFFu;   // |d2| bits
    double cur = __hiloint2double((int)kb, j);         // bit-concat composite key
    double m1 = fmax(cur, L[0]);
    double m2 = fmax(cur, L[1]);
    double m3 = fmax(cur, L[2]);
    double m4 = fmax(cur, L[3]);
    double m5 = fmax(cur, L[4]);
    double m6 = fmax(cur, L[5]);
    L[0] = fmin(L[0], cur);
    L[1] = fmin(L[1], m1);
    L[2] = fmin(L[2], m2);
    L[3] = fmin(L[3], m3);
    L[4] = fmin(L[4], m4);
    L[5] = fmin(L[5], m5);
    L[6] = fmin(L[6], m6);
  }

  unsigned resHi = 0, resLo = 0;
  for (int r = 0; r < NNB; ++r) {
    unsigned hi0 = (unsigned)__double2hiint(L[0]);
    unsigned lo0 = (unsigned)__double2loint(L[0]);
    unsigned gh = wave_min_dpp(hi0);
    gh = (unsigned)__builtin_amdgcn_readlane((int)gh, 63);
    unsigned lom = (hi0 == gh) ? lo0 : 0xFFFFFFFFu;
    unsigned gl = wave_min_dpp(lom);
    gl = (unsigned)__builtin_amdgcn_readlane((int)gl, 63);
    bool mine = (hi0 == gh) && (lo0 == gl);   // idx embedded -> unique owner
#pragma unroll
    for (int t = 0; t < LTOP - 1; ++t) L[t] = mine ? L[t + 1] : L[t];
    L[LTOP - 1] = mine ? INF : L[LTOP - 1];
    if (lane == r) { resHi = gh; resLo = gl; }
  }

  if (lane < NNB) {
    float dist = sqrtf(__uint_as_float(resHi));   // hi word IS the f32 |d2| key bits
    nbrD[(size_t)lane * NTOT + P] = dist;         // transposed [NNB][NTOT]
    nbrI[(size_t)lane * NTOT + P] = (int)resLo;   // lo word IS the index
    if (lane == 16) d16[P] = dist;                // dsort[:,16]
  }
}

// ---------------- Kernel C: fused radius + SHOT LRF + log-map + histogram ----------------
// 8 threads/block (2048 waves = 2/SIMD): trades lane utilization for wave-level latency
// hiding (R14: 256 waves = 0.25/SIMD exposed every dependent LDS/eigh op). Per-lane code
// identical -> bit-exact. Radius: same sequential f32 chain, d16 read direct from global
// (L2-hot). hist moved to LDS (runtime-indexed -> was scratch). Gathers issued before
// the chain so their latency hides under it.

__global__ __launch_bounds__(64) void shot_kernel(const float* __restrict__ coords,
                                                  const float* __restrict__ d16,
                                                  const float* __restrict__ nbrD,
                                                  const int* __restrict__ nbrI,
                                                  float* __restrict__ out) {
  __shared__ float ews[18 * WST];    // per-lane eigh workspace, stride WST
  __shared__ float hws[25 * WST];    // per-lane histogram, stride WST
  int lane = threadIdx.x;            // 0..WST-1
  int g = blockIdx.x * WST + lane;
  int b = g >> 12;
  int p = g & (NPTS - 1);
  const float* cb = coords + (size_t)b * NPTS * 3;
  const float* d16b = d16 + (size_t)b * NPTS;

  // issue all gathers before the radius chain (latency hides under it)
  int jj[NNB];
  float dd[NNB];
#pragma unroll
  for (int k = 0; k < NNB; ++k) {
    jj[k] = nbrI[(size_t)k * NTOT + g];
    dd[k] = nbrD[(size_t)k * NTOT + g];
  }
  float gx[NNB], gy[NNB], gz[NNB];
#pragma unroll
  for (int k = 0; k < NNB; ++k) {
    int j = jj[k];
    gx[k] = cb[j * 3 + 0];
    gy[k] = cb[j * 3 + 1];
    gz[k] = cb[j * 3 + 2];
  }
  float xi = cb[p * 3 + 0], yi = cb[p * 3 + 1], zi = cb[p * 3 + 2];

  // bit-identical sequential f32 radius chain (global reads, L2-hot, loads batchable)
  float s = 0.0f;
  for (int k = 0; k < NPTS; ++k) s += d16b[k];
  float radius = s / 4096.0f;

  float fill = 2.0f * radius / sqrtf(3.0f);

  float nbx[NNB], nby[NNB], nbz[NNB], dk[NNB];
#pragma unroll
  for (int k = 0; k < NNB; ++k) {
    float nx, ny, nz;
    if (dd[k] > radius) { nx = fill; ny = fill; nz = fill; }
    else {
      nx = gx[k] - xi;
      ny = gy[k] - yi;
      nz = gz[k] - zi;
    }
    nbx[k] = nx; nby[k] = ny; nbz[k] = nz;
    dk[k] = sqrtf((nx * nx + ny * ny) + nz * nz);
  }

  float wsum = 0.0f;
  float c00 = 0, c11 = 0, c22 = 0;
  float c01 = 0, c10 = 0, c02 = 0, c20 = 0, c12 = 0, c21 = 0;
  for (int k = 0; k < NNB; ++k) {
    float w = fmaxf(radius - dk[k], 0.0f);
    wsum += w;
    float wx = w * nbx[k], wy = w * nby[k], wz = w * nbz[k];
    c00 += wx * nbx[k]; c01 += wx * nby[k]; c02 += wx * nbz[k];
    c10 += wy * nbx[k]; c11 += wy * nby[k]; c12 += wy * nbz[k];
    c20 += wz * nbx[k]; c21 += wz * nby[k]; c22 += wz * nbz[k];
  }
  float den = wsum + 1e-12f;
  float a00 = c00 / den, a11 = c11 / den, a22 = c22 / den;
  float a01 = c01 / den, a10 = c10 / den;
  float a02 = c02 / den, a20 = c20 / den;
  float a12 = c12 / den, a21 = c21 / den;
  float A10 = 0.5f * (a01 + a10);
  float A20 = 0.5f * (a02 + a20);
  float A21 = 0.5f * (a12 + a21);

  float V[3][3];
  eigh3f_lds(a00, A10, A20, a11, A21, a22, &ews[lane], V);

  float xax0 = V[0][2], xax1 = V[1][2], xax2 = V[2][2];
  float zax0 = V[0][0], zax1 = V[1][0], zax2 = V[2][0];

  {
    int pos = 0, neg = 0;
    for (int k = 0; k < NNB; ++k) {
      float dt = (nbx[k] * xax0 + nby[k] * xax1) + nbz[k] * xax2;
      if (dt >= 0.0f) pos++; else neg++;
    }
    if (pos < neg) { xax0 = -xax0; xax1 = -xax1; xax2 = -xax2; }
  }
  {
    int pos = 0, neg = 0;
    for (int k = 0; k < NNB; ++k) {
      float dt = (nbx[k] * zax0 + nby[k] * zax1) + nbz[k] * zax2;
      if (dt >= 0.0f) pos++; else neg++;
    }
    if (pos < neg) { zax0 = -zax0; zax1 = -zax1; zax2 = -zax2; }
  }
  float yax0 = zax1 * xax2 - zax2 * xax1;
  float yax1 = zax2 * xax0 - zax0 * xax2;
  float yax2 = zax0 * xax1 - zax1 * xax0;

  // histogram in LDS (runtime bin index -> scratch if in registers)
  float* hh = &hws[lane];
#pragma unroll
  for (int k = 0; k < NBINS * NBINS; ++k) hh[k * WST] = 0.0f;
  float stp = 2.0f * radius / (float)NBINS;
  for (int k = 0; k < NNB; ++k) {
    float u = (nbx[k] * xax0 + nby[k] * xax1) + nbz[k] * xax2;
    float v = (nbx[k] * yax0 + nby[k] * yax1) + nbz[k] * yax2;
    float pn = sqrtf(u * u + v * v);
    float sc = dk[k] / (pn + 1e-12f);
    float pu = u * sc, pv = v * sc;
    float bxf = floorf((pu + radius) / stp);
    float byf = floorf((pv + radius) / stp);
    if (bxf >= 0.0f && bxf < (float)NBINS && byf >= 0.0f && byf < (float)NBINS) {
      int bx = (int)bxf, by = (int)byf;
      hh[(by * NBINS + bx) * WST] += 1.0f;
    }
  }
  float cvals[NBINS];
#pragma unroll
  for (int i = 0; i < NBINS; ++i) cvals[i] = ((float)i * stp - radius) + 0.5f * stp;
  float nrm2 = 0.0f;
  float hreg[NBINS * NBINS];
#pragma unroll
  for (int i = 0; i < NBINS; ++i) {
#pragma unroll
    for (int j = 0; j < NBINS; ++j) {
      float wgt = radius - sqrtf(cvals[i] * cvals[i] + cvals[j] * cvals[j]);
      float h = hh[(i * NBINS + j) * WST] * wgt;
      hreg[i * NBINS + j] = h;
      nrm2 += h * h;
    }
  }
  float nrm = sqrtf(nrm2);
#pragma unroll
  for (int k = 0; k < NBINS * NBINS; ++k) {
    out[(size_t)g * (NBINS * NBINS) + k] = hreg[k] / nrm;
  }
}

// ---------------- Launch ----------------

extern "C" void kernel_launch(void* const* d_in, const int* in_sizes, int n_in,
                              void* d_out, int out_size, void* d_ws, size_t ws_size,
                              hipStream_t stream) {
  const float* coords = (const float*)d_in[0];
  float* out = (float*)d_out;

  float* wsf = (float*)d_ws;
  float* d16 = wsf + 8;                           // 16384 floats
  float* nbrD = wsf + 8 + (size_t)NTOT;           // [NNB][NTOT] floats
  int* nbrI = (int*)(nbrD + (size_t)NNB * NTOT);  // [NNB][NTOT] ints

  knn_kernel<<<NTOT / 16, 1024, 0, stream>>>(coords, nbrD, nbrI, d16);
  shot_kernel<<<NTOT / WST, WST, 0, stream>>>(coords, d16, nbrD, nbrI, out);
}

// Round 16
// 153.782 us; speedup vs baseline: 1.1659x; 1.1659x over previous
//
#include <hip/hip_runtime.h>
#include <math.h>

// Match XLA/LAPACK f32 rounding: no FMA contraction anywhere in this file.
#pragma clang fp contract(off)

#define NPTS 4096
#define NBATCH 4
#define NTOT (NBATCH * NPTS)
#define NNB 20
#define NBINS 5
#define LTOP 7    // per-lane top-list size; P(lane holds >=8 of top-20) ~ 5e-4 total
#define PPB 4     // shot: points per 64-thread block (16 replica lanes/point) -> 4096 waves

// f32 LAPACK machine constants
#define SEPS    5.9604644775390625e-8f   // SLAMCH('E') = 2^-24
#define SSAFMIN 1.17549435e-38f          // SLAMCH('S') = 2^-126

// ---------------- LAPACK helpers (f32, faithful to reference LAPACK >= 3.10) ----------------

__device__ __forceinline__ float f_signf(float a, float b) {
  return __builtin_signbit(b) ? -fabsf(a) : fabsf(a);
}

__device__ float slapy2_(float x, float y) {
  float xa = fabsf(x), ya = fabsf(y);
  float w = fmaxf(xa, ya), z = fminf(xa, ya);
  if (z == 0.0f) return w;
  float t = z / w;
  return w * sqrtf(1.0f + t * t);
}

// LAPACK >= 3.10 slartg (c = |f|/d >= 0, r = sign(f)*d); unscaled path (values are moderate)
__device__ void slartg_(float f, float g, float* c, float* s, float* r) {
  if (g == 0.0f) {
    *c = 1.0f; *s = 0.0f; *r = f;
  } else if (f == 0.0f) {
    *c = 0.0f; *s = __builtin_signbit(g) ? -1.0f : 1.0f; *r = fabsf(g);
  } else {
    float f1 = fabsf(f);
    float d = sqrtf(f * f + g * g);
    *c = f1 / d;
    float rr = __builtin_signbit(f) ? -d : d;
    *r = rr;
    *s = g / rr;
  }
}

__device__ void slaev2_(float a, float b, float c,
                        float* rt1, float* rt2, float* cs1, float* sn1) {
  float sm = a + c;
  float df = a - c;
  float adf = fabsf(df);
  float tb = b + b;
  float ab = fabsf(tb);
  float acmx, acmn;
  if (fabsf(a) > fabsf(c)) { acmx = a; acmn = c; } else { acmx = c; acmn = a; }
  float rt;
  if (adf > ab)      { float t = ab / adf; rt = adf * sqrtf(1.0f + t * t); }
  else if (adf < ab) { float t = adf / ab; rt = ab * sqrtf(1.0f + t * t); }
  else               { rt = ab * sqrtf(2.0f); }
  int sgn1;
  if (sm < 0.0f) {
    *rt1 = 0.5f * (sm - rt); sgn1 = -1;
    *rt2 = (acmx / *rt1) * acmn - (b / *rt1) * b;
  } else if (sm > 0.0f) {
    *rt1 = 0.5f * (sm + rt); sgn1 = 1;
    *rt2 = (acmx / *rt1) * acmn - (b / *rt1) * b;
  } else {
    *rt1 = 0.5f * rt; *rt2 = -0.5f * rt; sgn1 = 1;
  }
  float cs; int sgn2;
  if (df >= 0.0f) { cs = df + rt; sgn2 = 1; }
  else            { cs = df - rt; sgn2 = -1; }
  float acs = fabsf(cs);
  float csv, snv;
  if (acs > ab) {
    float ct = -tb / cs;
    snv = 1.0f / sqrtf(1.0f + ct * ct);
    csv = ct * snv;
  } else {
    if (ab == 0.0f) { csv = 1.0f; snv = 0.0f; }
    else {
      float tn = -cs / tb;
      csv = 1.0f / sqrtf(1.0f + tn * tn);
      snv = tn * csv;
    }
  }
  if (sgn1 == sgn2) { float tn = csv; csv = -snv; snv = tn; }
  *cs1 = csv; *sn1 = snv;
}

// Per-point LDS workspace accessors: element i of point slot lives at w[i*PPB].
// Replica lanes of the same point write identical values simultaneously (benign race).
#define DD(i)    w[(i) * PPB]
#define EE(i)    w[(3 + (i)) * PPB]
#define ZZ(i, j) w[(5 + (i) * 3 + (j)) * PPB]
#define CC(i)    w[(14 + (i)) * PPB]
#define SN(i)    w[(16 + (i)) * PPB]

// SSTEQR('I', n=3) faithful port; arrays in LDS (runtime-indexed -> scratch otherwise)
__device__ void ssteqr3_lds(float* w) {
  const int n = 3;
  const float eps = SEPS;
  const float eps2 = SEPS * SEPS;
  const float safmin = SSAFMIN;
  const int nmaxit = 90;
  int jtot = 0;
  int l1 = 1;
  int l = 0, lsv = 0, lend = 0, lendsv = 0, m = 0, mm = 0;
  float p = 0, g = 0, r = 0, c = 0, s = 0, f = 0, bb = 0, rt1 = 0, rt2 = 0;
  float anorm = 0, tst = 0;

L10:
  if (l1 > n) goto L160;
  if (l1 > 1) EE(l1 - 2) = 0.0f;
  if (l1 <= n - 1) {
    for (m = l1; m <= n - 1; ++m) {
      tst = fabsf(EE(m - 1));
      if (tst == 0.0f) goto L30;
      if (tst <= (sqrtf(fabsf(DD(m - 1))) * sqrtf(fabsf(DD(m)))) * eps) {
        EE(m - 1) = 0.0f;
        goto L30;
      }
    }
  }
  m = n;
L30:
  l = l1; lsv = l; lend = m; lendsv = lend; l1 = m + 1;
  if (lend == l) goto L10;
  anorm = 0.0f;
  for (int i = l; i <= lend; ++i) anorm = fmaxf(anorm, fabsf(DD(i - 1)));
  for (int i = l; i <= lend - 1; ++i) anorm = fmaxf(anorm, fabsf(EE(i - 1)));
  if (anorm == 0.0f) goto L10;
  if (fabsf(DD(lend - 1)) < fabsf(DD(l - 1))) { lend = lsv; l = lendsv; }

  if (lend > l) {
L40:
    if (l != lend) {
      for (m = l; m <= lend - 1; ++m) {
        tst = EE(m - 1) * EE(m - 1);
        if (tst <= (eps2 * fabsf(DD(m - 1))) * fabsf(DD(m)) + safmin) goto L60;
      }
    }
    m = lend;
L60:
    if (m < lend) EE(m - 1) = 0.0f;
    p = DD(l - 1);
    if (m == l) goto L80;
    if (m == l + 1) {
      slaev2_(DD(l - 1), EE(l - 1), DD(l), &rt1, &rt2, &c, &s);
      for (int i = 0; i < n; ++i) {
        float tz = ZZ(i, l);
        ZZ(i, l)     = c * tz - s * ZZ(i, l - 1);
        ZZ(i, l - 1) = s * tz + c * ZZ(i, l - 1);
      }
      DD(l - 1) = rt1; DD(l) = rt2; EE(l - 1) = 0.0f;
      l += 2;
      if (l <= lend) goto L40;
      goto L140;
    }
    if (jtot == nmaxit) goto L140;
    jtot++;
    g = (DD(l) - p) / (2.0f * EE(l - 1));
    r = slapy2_(g, 1.0f);
    g = DD(m - 1) - p + EE(l - 1) / (g + f_signf(r, g));
    s = 1.0f; c = 1.0f; p = 0.0f;
    for (int i = m - 1; i >= l; --i) {
      f = s * EE(i - 1);
      bb = c * EE(i - 1);
      slartg_(g, f, &c, &s, &r);
      if (i != m - 1) EE(i) = r;
      g = DD(i) - p;
      r = (DD(i - 1) - g) * s + 2.0f * c * bb;
      p = s * r;
      DD(i) = g + p;
      g = c * r - bb;
      CC(i - 1) = c; SN(i - 1) = -s;
    }
    mm = m - l + 1;
    for (int j = mm - 1; j >= 1; --j) {
      float ct = CC(l + j - 2), st = SN(l + j - 2);
      for (int i = 0; i < n; ++i) {
        float tz = ZZ(i, l + j - 1);
        ZZ(i, l + j - 1) = ct * tz - st * ZZ(i, l + j - 2);
        ZZ(i, l + j - 2) = st * tz + ct * ZZ(i, l + j - 2);
      }
    }
    DD(l - 1) -= p;
    EE(l - 1) = g;
    goto L40;
L80:
    DD(l - 1) = p;
    l++;
    if (l <= lend) goto L40;
    goto L140;
  } else {
L90:
    if (l != lend) {
      for (m = l; m >= lend + 1; --m) {
        tst = EE(m - 2) * EE(m - 2);
        if (tst <= (eps2 * fabsf(DD(m - 1))) * fabsf(DD(m - 2)) + safmin) goto L110;
      }
    }
    m = lend;
L110:
    if (m > lend) EE(m - 2) = 0.0f;
    p = DD(l - 1);
    if (m == l) goto L130;
    if (m == l - 1) {
      slaev2_(DD(l - 2), EE(l - 2), DD(l - 1), &rt1, &rt2, &c, &s);
      for (int i = 0; i < n; ++i) {
        float tz = ZZ(i, l - 1);
        ZZ(i, l - 1) = c * tz - s * ZZ(i, l - 2);
        ZZ(i, l - 2) = s * tz + c * ZZ(i, l - 2);
      }
      DD(l - 2) = rt1; DD(l - 1) = rt2; EE(l - 2) = 0.0f;
      l -= 2;
      if (l >= lend) goto L90;
      goto L140;
    }
    if (jtot == nmaxit) goto L140;
    jtot++;
    g = (DD(l - 2) - p) / (2.0f * EE(l - 2));
    r = slapy2_(g, 1.0f);
    g = DD(m - 1) - p + EE(l - 2) / (g + f_signf(r, g));
    s = 1.0f; c = 1.0f; p = 0.0f;
    for (int i = m; i <= l - 1; ++i) {
      f = s * EE(i - 1);
      bb = c * EE(i - 1);
      slartg_(g, f, &c, &s, &r);
      if (i != m) EE(i - 2) = r;
      g = DD(i - 1) - p;
      r = (DD(i) - g) * s + 2.0f * c * bb;
      p = s * r;
      DD(i - 1) = g + p;
      g = c * r - bb;
      CC(i - 1) = c; SN(i - 1) = s;
    }
    mm = l - m + 1;
    for (int j = 1; j <= mm - 1; ++j) {
      float ct = CC(m + j - 2), st = SN(m + j - 2);
      for (int i = 0; i < n; ++i) {
        float tz = ZZ(i, m + j - 1);
        ZZ(i, m + j - 1) = ct * tz - st * ZZ(i, m + j - 2);
        ZZ(i, m + j - 2) = st * tz + ct * ZZ(i, m + j - 2);
      }
    }
    DD(l - 1) -= p;
    EE(l - 2) = g;
    goto L90;
L130:
    DD(l - 1) = p;
    l--;
    if (l >= lend) goto L90;
    goto L140;
  }
L140:
  if (jtot < nmaxit) goto L10;
  goto L160;
L160:
  for (int ii = 2; ii <= n; ++ii) {
    int i = ii - 1, k = i;
    float pp = DD(i - 1);
    for (int j = ii; j <= n; ++j)
      if (DD(j - 1) < pp) { k = j; pp = DD(j - 1); }
    if (k != i) {
      DD(k - 1) = DD(i - 1); DD(i - 1) = pp;
      for (int row = 0; row < n; ++row) {
        float t2 = ZZ(row, i - 1); ZZ(row, i - 1) = ZZ(row, k - 1); ZZ(row, k - 1) = t2;
      }
    }
  }
}

// ssyevd('V','L') for 3x3: ssytd2 -> ssteqr('I') -> sormtr. Workspace in LDS.
__device__ void eigh3f_lds(float A00, float A10, float A20, float A11, float A21, float A22,
                           float* w, float V[3][3]) {
  float taui, v2, beta;
  float alpha = A10;
  float xnorm = fabsf(A20);
  if (xnorm == 0.0f) {
    taui = 0.0f; beta = alpha; v2 = 0.0f;
  } else {
    beta = -f_signf(slapy2_(alpha, xnorm), alpha);
    taui = (beta - alpha) / beta;
    v2 = A20 * (1.0f / (alpha - beta));
  }
  float a11 = A11, a21 = A21, a22 = A22;
  if (taui != 0.0f) {
    float w0 = taui * (a11 + a21 * v2);
    float w1 = taui * (a21 + a22 * v2);
    float al = -0.5f * taui * (w0 + w1 * v2);
    w0 += al; w1 += al * v2;
    a11 -= 2.0f * w0;
    a21 -= (v2 * w0 + w1);
    a22 -= 2.0f * (v2 * w1);
  }
  DD(0) = A00; DD(1) = a11; DD(2) = a22;
  EE(0) = beta; EE(1) = a21;
  ZZ(0, 0) = 1.0f; ZZ(0, 1) = 0.0f; ZZ(0, 2) = 0.0f;
  ZZ(1, 0) = 0.0f; ZZ(1, 1) = 1.0f; ZZ(1, 2) = 0.0f;
  ZZ(2, 0) = 0.0f; ZZ(2, 1) = 0.0f; ZZ(2, 2) = 1.0f;

  ssteqr3_lds(w);

  for (int k = 0; k < 3; ++k) {
    float t = taui * (ZZ(1, k) + v2 * ZZ(2, k));
    ZZ(1, k) -= t;
    ZZ(2, k) -= t * v2;
  }
  for (int i = 0; i < 3; ++i)
    for (int k = 0; k < 3; ++k) V[i][k] = ZZ(i, k);
}

// wave64 u32 min-reduce via DPP (row_shr 1/2/4/8 + row_bcast15/31); result valid in lane 63.
__device__ __forceinline__ unsigned wave_min_dpp(unsigned v) {
  unsigned t;
  t = (unsigned)__builtin_amdgcn_update_dpp(-1, (int)v, 0x111, 0xf, 0xf, false); v = t < v ? t : v;
  t = (unsigned)__builtin_amdgcn_update_dpp(-1, (int)v, 0x112, 0xf, 0xf, false); v = t < v ? t : v;
  t = (unsigned)__builtin_amdgcn_update_dpp(-1, (int)v, 0x114, 0xf, 0xf, false); v = t < v ? t : v;
  t = (unsigned)__builtin_amdgcn_update_dpp(-1, (int)v, 0x118, 0xf, 0xf, false); v = t < v ? t : v;
  t = (unsigned)__builtin_amdgcn_update_dpp(-1, (int)v, 0x142, 0xa, 0xf, false); v = t < v ? t : v;
  t = (unsigned)__builtin_amdgcn_update_dpp(-1, (int)v, 0x143, 0xc, 0xf, false); v = t < v ? t : v;
  return v;
}

// ---------------- Kernel A: wave-per-point KNN (FROZEN at R12 best: 72.3 us) ----------------

__global__ __launch_bounds__(1024, 8) void knn_kernel(const float* __restrict__ coords,
                                                      float* __restrict__ nbrD,
                                                      int* __restrict__ nbrI,
                                                      float* __restrict__ d16) {
  __shared__ float4 scs[NPTS];     // 64 KB: {x, y, z, sq}
  int tid = threadIdx.x;
  int wid = tid >> 6;
  int lane = tid & 63;
  int P = blockIdx.x * 16 + wid;   // 16 | 4096, no batch crossing
  int b = P >> 12;
  int p = P & (NPTS - 1);
  const float* cb = coords + (size_t)b * NPTS * 3;

  for (int i = tid; i < NPTS; i += 1024) {
    float x = cb[3 * i + 0], y = cb[3 * i + 1], z = cb[3 * i + 2];
    float sq = (x * x + y * y) + z * z;   // exact ref expression order
    scs[i] = make_float4(x, y, z, sq);
  }
  __syncthreads();

  float4 ci = scs[p];
  float xi = ci.x, yi = ci.y, zi = ci.z, sqi = ci.w;

  const double INF = __hiloint2double(0x7FF00000, 0);   // +inf sentinel (> any composite)
  double L[LTOP];
#pragma unroll
  for (int t = 0; t < LTOP; ++t) L[t] = INF;

#pragma unroll 8
  for (int k = 0; k < NPTS / 64; ++k) {
    int j = k * 64 + lane;
    float4 cj = scs[j];                       // one ds_read_b128
    float dot = (xi * cj.x + yi * cj.y) + zi * cj.z;
    float d2 = (sqi - 2.0f * dot) + cj.w;     // exact ref expression order
    unsigned kb = __float_as_uint(d2) & 0x7FFFFFFFu;   // |d2| bits
    double cur = __hiloint2double((int)kb, j);         // bit-concat composite key
    double m1 = fmax(cur, L[0]);
    double m2 = fmax(cur, L[1]);
    double m3 = fmax(cur, L[2]);
    double m4 = fmax(cur, L[3]);
    double m5 = fmax(cur, L[4]);
    double m6 = fmax(cur, L[5]);
    L[0] = fmin(L[0], cur);
    L[1] = fmin(L[1], m1);
    L[2] = fmin(L[2], m2);
    L[3] = fmin(L[3], m3);
    L[4] = fmin(L[4], m4);
    L[5] = fmin(L[5], m5);
    L[6] = fmin(L[6], m6);
  }

  unsigned resHi = 0, resLo = 0;
  for (int r = 0; r < NNB; ++r) {
    unsigned hi0 = (unsigned)__double2hiint(L[0]);
    unsigned lo0 = (unsigned)__double2loint(L[0]);
    unsigned gh = wave_min_dpp(hi0);
    gh = (unsigned)__builtin_amdgcn_readlane((int)gh, 63);
    unsigned lom = (hi0 == gh) ? lo0 : 0xFFFFFFFFu;
    unsigned gl = wave_min_dpp(lom);
    gl = (unsigned)__builtin_amdgcn_readlane((int)gl, 63);
    bool mine = (hi0 == gh) && (lo0 == gl);   // idx embedded -> unique owner
#pragma unroll
    for (int t = 0; t < LTOP - 1; ++t) L[t] = mine ? L[t + 1] : L[t];
    L[LTOP - 1] = mine ? INF : L[LTOP - 1];
    if (lane == r) { resHi = gh; resLo = gl; }
  }

  if (lane < NNB) {
    float dist = sqrtf(__uint_as_float(resHi));   // hi word IS the f32 |d2| key bits
    nbrD[(size_t)lane * NTOT + P] = dist;         // transposed [NNB][NTOT]
    nbrI[(size_t)lane * NTOT + P] = (int)resLo;   // lo word IS the index
    if (lane == 16) d16[P] = dist;                // dsort[:,16]
  }
}

// ---------------- Kernel B: per-batch radius = mean(d16) (R12 proven version) ----------------
// Bit-identical sequential f32 sum; coalesced LDS stage then all 64 lanes redundantly
// run the same dependent add chain on LDS broadcast reads.

__global__ __launch_bounds__(64) void radius_kernel(const float* __restrict__ d16,
                                                    float* __restrict__ radius) {
  __shared__ float buf[NPTS];   // 16 KB
  int b = blockIdx.x;
  int lane = threadIdx.x;
  for (int i = lane; i < NPTS; i += 64) buf[i] = d16[(size_t)b * NPTS + i];
  __syncthreads();
  float s = 0.0f;
  for (int k = 0; k < NPTS; ++k) s += buf[k];   // same-addr LDS reads broadcast; same order
  if (lane == 0) radius[b] = s / 4096.0f;
}

// ---------------- Kernel C: per-point SHOT LRF + log-map + histogram ----------------
// 64-thread blocks, PPB=4 points/block, 16 replica lanes per point (lockstep-identical
// ops; same-address LDS writes carry identical values -> deterministic). Waves:
// 256 -> 4096 (4/SIMD) so eigh/gather latency interleaves across waves (R14 had
// 0.25 waves/SIMD -> every stall exposed). Eigh workspace + hist in LDS (stride PPB).

__global__ __launch_bounds__(64) void shot_kernel(const float* __restrict__ coords,
                                                  const float* __restrict__ radius_arr,
                                                  const float* __restrict__ nbrD,
                                                  const int* __restrict__ nbrI,
                                                  float* __restrict__ out) {
  __shared__ float ews[18 * PPB];    // per-point eigh workspace, stride PPB
  __shared__ float hws[25 * PPB];    // per-point histogram, stride PPB
  int lane = threadIdx.x;
  int pid = lane & (PPB - 1);        // point slot within block
  int g = blockIdx.x * PPB + pid;    // grid exact: NTOT/PPB blocks
  int b = g >> 12;
  int p = g & (NPTS - 1);
  const float* cb = coords + (size_t)b * NPTS * 3;
  float radius = radius_arr[b];

  int jj[NNB];
  float dd[NNB];
#pragma unroll
  for (int k = 0; k < NNB; ++k) {
    jj[k] = nbrI[(size_t)k * NTOT + g];
    dd[k] = nbrD[(size_t)k * NTOT + g];
  }
  float xi = cb[p * 3 + 0], yi = cb[p * 3 + 1], zi = cb[p * 3 + 2];
  float fill = 2.0f * radius / sqrtf(3.0f);

  float nbx[NNB], nby[NNB], nbz[NNB], dk[NNB];
#pragma unroll
  for (int k = 0; k < NNB; ++k) {
    int j = jj[k];
    float nx, ny, nz;
    if (dd[k] > radius) { nx = fill; ny = fill; nz = fill; }
    else {
      nx = cb[j * 3 + 0] - xi;
      ny = cb[j * 3 + 1] - yi;
      nz = cb[j * 3 + 2] - zi;
    }
    nbx[k] = nx; nby[k] = ny; nbz[k] = nz;
    dk[k] = sqrtf((nx * nx + ny * ny) + nz * nz);
  }

  float wsum = 0.0f;
  float c00 = 0, c11 = 0, c22 = 0;
  float c01 = 0, c10 = 0, c02 = 0, c20 = 0, c12 = 0, c21 = 0;
  for (int k = 0; k < NNB; ++k) {
    float w = fmaxf(radius - dk[k], 0.0f);
    wsum += w;
    float wx = w * nbx[k], wy = w * nby[k], wz = w * nbz[k];
    c00 += wx * nbx[k]; c01 += wx * nby[k]; c02 += wx * nbz[k];
    c10 += wy * nbx[k]; c11 += wy * nby[k]; c12 += wy * nbz[k];
    c20 += wz * nbx[k]; c21 += wz * nby[k]; c22 += wz * nbz[k];
  }
  float den = wsum + 1e-12f;
  float a00 = c00 / den, a11 = c11 / den, a22 = c22 / den;
  float a01 = c01 / den, a10 = c10 / den;
  float a02 = c02 / den, a20 = c20 / den;
  float a12 = c12 / den, a21 = c21 / den;
  float A10 = 0.5f * (a01 + a10);
  float A20 = 0.5f * (a02 + a20);
  float A21 = 0.5f * (a12 + a21);

  float V[3][3];
  eigh3f_lds(a00, A10, A20, a11, A21, a22, &ews[pid], V);

  float xax0 = V[0][2], xax1 = V[1][2], xax2 = V[2][2];
  float zax0 = V[0][0], zax1 = V[1][0], zax2 = V[2][0];

  {
    int pos = 0, neg = 0;
    for (int k = 0; k < NNB; ++k) {
      float dt = (nbx[k] * xax0 + nby[k] * xax1) + nbz[k] * xax2;
      if (dt >= 0.0f) pos++; else neg++;
    }
    if (pos < neg) { xax0 = -xax0; xax1 = -xax1; xax2 = -xax2; }
  }
  {
    int pos = 0, neg = 0;
    for (int k = 0; k < NNB; ++k) {
      float dt = (nbx[k] * zax0 + nby[k] * zax1) + nbz[k] * zax2;
      if (dt >= 0.0f) pos++; else neg++;
    }
    if (pos < neg) { zax0 = -zax0; zax1 = -zax1; zax2 = -zax2; }
  }
  float yax0 = zax1 * xax2 - zax2 * xax1;
  float yax1 = zax2 * xax0 - zax0 * xax2;
  float yax2 = zax0 * xax1 - zax1 * xax0;

  // histogram in LDS (runtime bin index -> scratch if in registers)
  float* hh = &hws[pid];
#pragma unroll
  for (int k = 0; k < NBINS * NBINS; ++k) hh[k * PPB] = 0.0f;
  float stp = 2.0f * radius / (float)NBINS;
  for (int k = 0; k < NNB; ++k) {
    float u = (nbx[k] * xax0 + nby[k] * xax1) + nbz[k] * xax2;
    float v = (nbx[k] * yax0 + nby[k] * yax1) + nbz[k] * yax2;
    float pn = sqrtf(u * u + v * v);
    float sc = dk[k] / (pn + 1e-12f);
    float pu = u * sc, pv = v * sc;
    float bxf = floorf((pu + radius) / stp);
    float byf = floorf((pv + radius) / stp);
    if (bxf >= 0.0f && bxf < (float)NBINS && byf >= 0.0f && byf < (float)NBINS) {
      int bx = (int)bxf, by = (int)byf;
      hh[(by * NBINS + bx) * PPB] += 1.0f;   // replicas write identical values
    }
  }
  float cvals[NBINS];
#pragma unroll
  for (int i = 0; i < NBINS; ++i) cvals[i] = ((float)i * stp - radius) + 0.5f * stp;
  float nrm2 = 0.0f;
  float hreg[NBINS * NBINS];
#pragma unroll
  for (int i = 0; i < NBINS; ++i) {
#pragma unroll
    for (int j = 0; j < NBINS; ++j) {
      float wgt = radius - sqrtf(cvals[i] * cvals[i] + cvals[j] * cvals[j]);
      float h = hh[(i * NBINS + j) * PPB] * wgt;
      hreg[i * NBINS + j] = h;
      nrm2 += h * h;
    }
  }
  float nrm = sqrtf(nrm2);
  if (lane < PPB) {   // one replica writes
#pragma unroll
    for (int k = 0; k < NBINS * NBINS; ++k) {
      out[(size_t)g * (NBINS * NBINS) + k] = hreg[k] / nrm;
    }
  }
}

// ---------------- Launch ----------------

extern "C" void kernel_launch(void* const* d_in, const int* in_sizes, int n_in,
                              void* d_out, int out_size, void* d_ws, size_t ws_size,
                              hipStream_t stream) {
  const float* coords = (const float*)d_in[0];
  float* out = (float*)d_out;

  float* wsf = (float*)d_ws;
  float* radius = wsf;                            // 4 floats (+pad to 8)
  float* d16 = wsf + 8;                           // 16384 floats
  float* nbrD = wsf + 8 + (size_t)NTOT;           // [NNB][NTOT] floats
  int* nbrI = (int*)(nbrD + (size_t)NNB * NTOT);  // [NNB][NTOT] ints

  knn_kernel<<<NTOT / 16, 1024, 0, stream>>>(coords, nbrD, nbrI, d16);
  radius_kernel<<<NBATCH, 64, 0, stream>>>(d16, radius);
  shot_kernel<<<NTOT / PPB, 64, 0, stream>>>(coords, radius, nbrD, nbrI, out);
}

// Round 17
// 115.967 us; speedup vs baseline: 1.5461x; 1.3261x over previous
//
#include <hip/hip_runtime.h>
#include <math.h>

// Match XLA/LAPACK f32 rounding: no FMA contraction anywhere in this file.
#pragma clang fp contract(off)

#define NPTS 4096
#define NBATCH 4
#define NTOT (NBATCH * NPTS)
#define NNB 20
#define NBINS 5
#define LTOP 7    // per-lane top-list size; P(lane holds >=8 of top-20) ~ 5e-4 total

// f32 LAPACK machine constants
#define SEPS    5.9604644775390625e-8f   // SLAMCH('E') = 2^-24
#define SSAFMIN 1.17549435e-38f          // SLAMCH('S') = 2^-126

// ---------------- LAPACK helpers (f32, faithful to reference LAPACK >= 3.10) ----------------

__device__ __forceinline__ float f_signf(float a, float b) {
  return __builtin_signbit(b) ? -fabsf(a) : fabsf(a);
}

__device__ float slapy2_(float x, float y) {
  float xa = fabsf(x), ya = fabsf(y);
  float w = fmaxf(xa, ya), z = fminf(xa, ya);
  if (z == 0.0f) return w;
  float t = z / w;
  return w * sqrtf(1.0f + t * t);
}

// LAPACK >= 3.10 slartg (c = |f|/d >= 0, r = sign(f)*d); unscaled path (values are moderate)
__device__ void slartg_(float f, float g, float* c, float* s, float* r) {
  if (g == 0.0f) {
    *c = 1.0f; *s = 0.0f; *r = f;
  } else if (f == 0.0f) {
    *c = 0.0f; *s = __builtin_signbit(g) ? -1.0f : 1.0f; *r = fabsf(g);
  } else {
    float f1 = fabsf(f);
    float d = sqrtf(f * f + g * g);
    *c = f1 / d;
    float rr = __builtin_signbit(f) ? -d : d;
    *r = rr;
    *s = g / rr;
  }
}

__device__ void slaev2_(float a, float b, float c,
                        float* rt1, float* rt2, float* cs1, float* sn1) {
  float sm = a + c;
  float df = a - c;
  float adf = fabsf(df);
  float tb = b + b;
  float ab = fabsf(tb);
  float acmx, acmn;
  if (fabsf(a) > fabsf(c)) { acmx = a; acmn = c; } else { acmx = c; acmn = a; }
  float rt;
  if (adf > ab)      { float t = ab / adf; rt = adf * sqrtf(1.0f + t * t); }
  else if (adf < ab) { float t = adf / ab; rt = ab * sqrtf(1.0f + t * t); }
  else               { rt = ab * sqrtf(2.0f); }
  int sgn1;
  if (sm < 0.0f) {
    *rt1 = 0.5f * (sm - rt); sgn1 = -1;
    *rt2 = (acmx / *rt1) * acmn - (b / *rt1) * b;
  } else if (sm > 0.0f) {
    *rt1 = 0.5f * (sm + rt); sgn1 = 1;
    *rt2 = (acmx / *rt1) * acmn - (b / *rt1) * b;
  } else {
    *rt1 = 0.5f * rt; *rt2 = -0.5f * rt; sgn1 = 1;
  }
  float cs; int sgn2;
  if (df >= 0.0f) { cs = df + rt; sgn2 = 1; }
  else            { cs = df - rt; sgn2 = -1; }
  float acs = fabsf(cs);
  float csv, snv;
  if (acs > ab) {
    float ct = -tb / cs;
    snv = 1.0f / sqrtf(1.0f + ct * ct);
    csv = ct * snv;
  } else {
    if (ab == 0.0f) { csv = 1.0f; snv = 0.0f; }
    else {
      float tn = -cs / tb;
      csv = 1.0f / sqrtf(1.0f + tn * tn);
      snv = tn * csv;
    }
  }
  if (sgn1 == sgn2) { float tn = csv; csv = -snv; snv = tn; }
  *cs1 = csv; *sn1 = snv;
}

// ---- register-resident runtime-index accessors (indices only span {0,1,2}) ----
__device__ __forceinline__ float sel3(float a0, float a1, float a2, int i) {
  float r = (i == 1) ? a1 : a0;
  return (i == 2) ? a2 : r;
}
__device__ __forceinline__ float sel2(float a0, float a1, int i) {
  return (i == 1) ? a1 : a0;
}
#define RD(i)   sel3(d0, d1, d2, (i))
#define RE(i)   sel2(e0, e1, (i))
#define RC(i)   sel2(c0r, c1r, (i))
#define RS(i)   sel2(s0r, s1r, (i))
#define WD(i,v) do{ float _t=(v); int _i=(i); d0=(_i==0)?_t:d0; d1=(_i==1)?_t:d1; d2=(_i==2)?_t:d2; }while(0)
#define WE(i,v) do{ float _t=(v); int _i=(i); e0=(_i==0)?_t:e0; e1=(_i==1)?_t:e1; }while(0)
#define WC(i,v) do{ float _t=(v); int _i=(i); c0r=(_i==0)?_t:c0r; c1r=(_i==1)?_t:c1r; }while(0)
#define WS(i,v) do{ float _t=(v); int _i=(i); s0r=(_i==0)?_t:s0r; s1r=(_i==1)?_t:s1r; }while(0)
// column rotation: t=Z[r][ja]; Z[r][ja]=c*t - s*Z[r][jb]; Z[r][jb]=s*t + c*Z[r][jb]
#define ZROT(ja, jb, cc, ss) do{ int _a=(ja), _b=(jb); float _c=(cc), _s=(ss);                       \
  { float ta=sel3(z00,z01,z02,_a), tb=sel3(z00,z01,z02,_b); float na=_c*ta-_s*tb, nb=_s*ta+_c*tb;   \
    z00=(_a==0)?na:((_b==0)?nb:z00); z01=(_a==1)?na:((_b==1)?nb:z01); z02=(_a==2)?na:((_b==2)?nb:z02);} \
  { float ta=sel3(z10,z11,z12,_a), tb=sel3(z10,z11,z12,_b); float na=_c*ta-_s*tb, nb=_s*ta+_c*tb;   \
    z10=(_a==0)?na:((_b==0)?nb:z10); z11=(_a==1)?na:((_b==1)?nb:z11); z12=(_a==2)?na:((_b==2)?nb:z12);} \
  { float ta=sel3(z20,z21,z22,_a), tb=sel3(z20,z21,z22,_b); float na=_c*ta-_s*tb, nb=_s*ta+_c*tb;   \
    z20=(_a==0)?na:((_b==0)?nb:z20); z21=(_a==1)?na:((_b==1)?nb:z21); z22=(_a==2)?na:((_b==2)?nb:z22);} \
}while(0)
// column swap ia <-> ib
#define ZSWAP(ia, ib) do{ int _a=(ia), _b=(ib);                                                     \
  { float ta=sel3(z00,z01,z02,_a), tb=sel3(z00,z01,z02,_b);                                         \
    z00=(_a==0)?tb:((_b==0)?ta:z00); z01=(_a==1)?tb:((_b==1)?ta:z01); z02=(_a==2)?tb:((_b==2)?ta:z02);} \
  { float ta=sel3(z10,z11,z12,_a), tb=sel3(z10,z11,z12,_b);                                         \
    z10=(_a==0)?tb:((_b==0)?ta:z10); z11=(_a==1)?tb:((_b==1)?ta:z11); z12=(_a==2)?tb:((_b==2)?ta:z12);} \
  { float ta=sel3(z20,z21,z22,_a), tb=sel3(z20,z21,z22,_b);                                         \
    z20=(_a==0)?tb:((_b==0)?ta:z20); z21=(_a==1)?tb:((_b==1)?ta:z21); z22=(_a==2)?tb:((_b==2)?ta:z22);} \
}while(0)

// ssyevd('V','L') for 3x3, fully register-resident (ssytd2 -> ssteqr('I') -> sormtr).
// Line-for-line port of the LDS version; only storage/access changed -> bit-exact.
__device__ void eigh3f_reg(float A00, float A10, float A20, float A11, float A21, float A22,
                           float V[3][3]) {
  float taui, v2, beta;
  float alpha = A10;
  float xnorm = fabsf(A20);
  if (xnorm == 0.0f) {
    taui = 0.0f; beta = alpha; v2 = 0.0f;
  } else {
    beta = -f_signf(slapy2_(alpha, xnorm), alpha);
    taui = (beta - alpha) / beta;
    v2 = A20 * (1.0f / (alpha - beta));
  }
  float a11 = A11, a21 = A21, a22 = A22;
  if (taui != 0.0f) {
    float w0 = taui * (a11 + a21 * v2);
    float w1 = taui * (a21 + a22 * v2);
    float al = -0.5f * taui * (w0 + w1 * v2);
    w0 += al; w1 += al * v2;
    a11 -= 2.0f * w0;
    a21 -= (v2 * w0 + w1);
    a22 -= 2.0f * (v2 * w1);
  }
  float d0 = A00, d1 = a11, d2 = a22;
  float e0 = beta, e1 = a21;
  float z00 = 1.0f, z01 = 0.0f, z02 = 0.0f;
  float z10 = 0.0f, z11 = 1.0f, z12 = 0.0f;
  float z20 = 0.0f, z21 = 0.0f, z22 = 1.0f;
  float c0r = 0.0f, c1r = 0.0f, s0r = 0.0f, s1r = 0.0f;

  // ---- SSTEQR('I', n=3) ----
  {
    const int n = 3;
    const float eps = SEPS;
    const float eps2 = SEPS * SEPS;
    const float safmin = SSAFMIN;
    const int nmaxit = 90;
    int jtot = 0;
    int l1 = 1;
    int l = 0, lsv = 0, lend = 0, lendsv = 0, m = 0, mm = 0;
    float p = 0, g = 0, r = 0, c = 0, s = 0, f = 0, bb = 0, rt1 = 0, rt2 = 0;
    float anorm = 0, tst = 0;

L10:
    if (l1 > n) goto L160;
    if (l1 > 1) WE(l1 - 2, 0.0f);
    if (l1 <= n - 1) {
      for (m = l1; m <= n - 1; ++m) {
        tst = fabsf(RE(m - 1));
        if (tst == 0.0f) goto L30;
        if (tst <= (sqrtf(fabsf(RD(m - 1))) * sqrtf(fabsf(RD(m)))) * eps) {
          WE(m - 1, 0.0f);
          goto L30;
        }
      }
    }
    m = n;
L30:
    l = l1; lsv = l; lend = m; lendsv = lend; l1 = m + 1;
    if (lend == l) goto L10;
    anorm = 0.0f;
    for (int i = l; i <= lend; ++i) anorm = fmaxf(anorm, fabsf(RD(i - 1)));
    for (int i = l; i <= lend - 1; ++i) anorm = fmaxf(anorm, fabsf(RE(i - 1)));
    if (anorm == 0.0f) goto L10;
    if (fabsf(RD(lend - 1)) < fabsf(RD(l - 1))) { lend = lsv; l = lendsv; }

    if (lend > l) {
L40:
      if (l != lend) {
        for (m = l; m <= lend - 1; ++m) {
          tst = RE(m - 1) * RE(m - 1);
          if (tst <= (eps2 * fabsf(RD(m - 1))) * fabsf(RD(m)) + safmin) goto L60;
        }
      }
      m = lend;
L60:
      if (m < lend) WE(m - 1, 0.0f);
      p = RD(l - 1);
      if (m == l) goto L80;
      if (m == l + 1) {
        slaev2_(RD(l - 1), RE(l - 1), RD(l), &rt1, &rt2, &c, &s);
        ZROT(l, l - 1, c, s);
        WD(l - 1, rt1); WD(l, rt2); WE(l - 1, 0.0f);
        l += 2;
        if (l <= lend) goto L40;
        goto L140;
      }
      if (jtot == nmaxit) goto L140;
      jtot++;
      g = (RD(l) - p) / (2.0f * RE(l - 1));
      r = slapy2_(g, 1.0f);
      g = RD(m - 1) - p + RE(l - 1) / (g + f_signf(r, g));
      s = 1.0f; c = 1.0f; p = 0.0f;
      for (int i = m - 1; i >= l; --i) {
        f = s * RE(i - 1);
        bb = c * RE(i - 1);
        slartg_(g, f, &c, &s, &r);
        if (i != m - 1) WE(i, r);
        g = RD(i) - p;
        r = (RD(i - 1) - g) * s + 2.0f * c * bb;
        p = s * r;
        WD(i, g + p);
        g = c * r - bb;
        WC(i - 1, c); WS(i - 1, -s);
      }
      mm = m - l + 1;
      for (int j = mm - 1; j >= 1; --j) {
        float ct = RC(l + j - 2), st = RS(l + j - 2);
        ZROT(l + j - 1, l + j - 2, ct, st);
      }
      WD(l - 1, RD(l - 1) - p);
      WE(l - 1, g);
      goto L40;
L80:
      WD(l - 1, p);
      l++;
      if (l <= lend) goto L40;
      goto L140;
    } else {
L90:
      if (l != lend) {
        for (m = l; m >= lend + 1; --m) {
          tst = RE(m - 2) * RE(m - 2);
          if (tst <= (eps2 * fabsf(RD(m - 1))) * fabsf(RD(m - 2)) + safmin) goto L110;
        }
      }
      m = lend;
L110:
      if (m > lend) WE(m - 2, 0.0f);
      p = RD(l - 1);
      if (m == l) goto L130;
      if (m == l - 1) {
        slaev2_(RD(l - 2), RE(l - 2), RD(l - 1), &rt1, &rt2, &c, &s);
        ZROT(l - 1, l - 2, c, s);
        WD(l - 2, rt1); WD(l - 1, rt2); WE(l - 2, 0.0f);
        l -= 2;
        if (l >= lend) goto L90;
        goto L140;
      }
      if (jtot == nmaxit) goto L140;
      jtot++;
      g = (RD(l - 2) - p) / (2.0f * RE(l - 2));
      r = slapy2_(g, 1.0f);
      g = RD(m - 1) - p + RE(l - 2) / (g + f_signf(r, g));
      s = 1.0f; c = 1.0f; p = 0.0f;
      for (int i = m; i <= l - 1; ++i) {
        f = s * RE(i - 1);
        bb = c * RE(i - 1);
        slartg_(g, f, &c, &s, &r);
        if (i != m) WE(i - 2, r);
        g = RD(i - 1) - p;
        r = (RD(i) - g) * s + 2.0f * c * bb;
        p = s * r;
        WD(i - 1, g + p);
        g = c * r - bb;
        WC(i - 1, c); WS(i - 1, s);
      }
      mm = l - m + 1;
      for (int j = 1; j <= mm - 1; ++j) {
        float ct = RC(m + j - 2), st = RS(m + j - 2);
        ZROT(m + j - 1, m + j - 2, ct, st);
      }
      WD(l - 1, RD(l - 1) - p);
      WE(l - 2, g);
      goto L90;
L130:
      WD(l - 1, p);
      l--;
      if (l >= lend) goto L90;
      goto L140;
    }
L140:
    if (jtot < nmaxit) goto L10;
    goto L160;
L160:
    // selection sort ascending, swap eigenvector columns
    for (int ii = 2; ii <= n; ++ii) {
      int i = ii - 1, k = i;
      float pp = RD(i - 1);
      for (int j = ii; j <= n; ++j)
        if (RD(j - 1) < pp) { k = j; pp = RD(j - 1); }
      if (k != i) {
        WD(k - 1, RD(i - 1));
        WD(i - 1, pp);
        ZSWAP(i - 1, k - 1);
      }
    }
  }

  // ---- sormtr: Z := H1 * Z, H1 = I - tau*u*u^T, u = [0, 1, v2] ----
  {
    float t0 = taui * (z10 + v2 * z20);
    float t1 = taui * (z11 + v2 * z21);
    float t2 = taui * (z12 + v2 * z22);
    z10 -= t0; z20 -= t0 * v2;
    z11 -= t1; z21 -= t1 * v2;
    z12 -= t2; z22 -= t2 * v2;
  }
  V[0][0] = z00; V[0][1] = z01; V[0][2] = z02;
  V[1][0] = z10; V[1][1] = z11; V[1][2] = z12;
  V[2][0] = z20; V[2][1] = z21; V[2][2] = z22;
}

// wave64 u32 min-reduce via DPP (row_shr 1/2/4/8 + row_bcast15/31); result valid in lane 63.
__device__ __forceinline__ unsigned wave_min_dpp(unsigned v) {
  unsigned t;
  t = (unsigned)__builtin_amdgcn_update_dpp(-1, (int)v, 0x111, 0xf, 0xf, false); v = t < v ? t : v;
  t = (unsigned)__builtin_amdgcn_update_dpp(-1, (int)v, 0x112, 0xf, 0xf, false); v = t < v ? t : v;
  t = (unsigned)__builtin_amdgcn_update_dpp(-1, (int)v, 0x114, 0xf, 0xf, false); v = t < v ? t : v;
  t = (unsigned)__builtin_amdgcn_update_dpp(-1, (int)v, 0x118, 0xf, 0xf, false); v = t < v ? t : v;
  t = (unsigned)__builtin_amdgcn_update_dpp(-1, (int)v, 0x142, 0xa, 0xf, false); v = t < v ? t : v;
  t = (unsigned)__builtin_amdgcn_update_dpp(-1, (int)v, 0x143, 0xc, 0xf, false); v = t < v ? t : v;
  return v;
}

// ---------------- Kernel A: wave-per-point KNN (FROZEN at R12 best: 72.3 us) ----------------

__global__ __launch_bounds__(1024, 8) void knn_kernel(const float* __restrict__ coords,
                                                      float* __restrict__ nbrD,
                                                      int* __restrict__ nbrI,
                                                      float* __restrict__ d16) {
  __shared__ float4 scs[NPTS];     // 64 KB: {x, y, z, sq}
  int tid = threadIdx.x;
  int wid = tid >> 6;
  int lane = tid & 63;
  int P = blockIdx.x * 16 + wid;   // 16 | 4096, no batch crossing
  int b = P >> 12;
  int p = P & (NPTS - 1);
  const float* cb = coords + (size_t)b * NPTS * 3;

  for (int i = tid; i < NPTS; i += 1024) {
    float x = cb[3 * i + 0], y = cb[3 * i + 1], z = cb[3 * i + 2];
    float sq = (x * x + y * y) + z * z;   // exact ref expression order
    scs[i] = make_float4(x, y, z, sq);
  }
  __syncthreads();

  float4 ci = scs[p];
  float xi = ci.x, yi = ci.y, zi = ci.z, sqi = ci.w;

  const double INF = __hiloint2double(0x7FF00000, 0);   // +inf sentinel (> any composite)
  double L[LTOP];
#pragma unroll
  for (int t = 0; t < LTOP; ++t) L[t] = INF;

#pragma unroll 8
  for (int k = 0; k < NPTS / 64; ++k) {
    int j = k * 64 + lane;
    float4 cj = scs[j];                       // one ds_read_b128
    float dot = (xi * cj.x + yi * cj.y) + zi * cj.z;
    float d2 = (sqi - 2.0f * dot) + cj.w;     // exact ref expression order
    unsigned kb = __float_as_uint(d2) & 0x7FFFFFFFu;   // |d2| bits
    double cur = __hiloint2double((int)kb, j);         // bit-concat composite key
    double m1 = fmax(cur, L[0]);
    double m2 = fmax(cur, L[1]);
    double m3 = fmax(cur, L[2]);
    double m4 = fmax(cur, L[3]);
    double m5 = fmax(cur, L[4]);
    double m6 = fmax(cur, L[5]);
    L[0] = fmin(L[0], cur);
    L[1] = fmin(L[1], m1);
    L[2] = fmin(L[2], m2);
    L[3] = fmin(L[3], m3);
    L[4] = fmin(L[4], m4);
    L[5] = fmin(L[5], m5);
    L[6] = fmin(L[6], m6);
  }

  unsigned resHi = 0, resLo = 0;
  for (int r = 0; r < NNB; ++r) {
    unsigned hi0 = (unsigned)__double2hiint(L[0]);
    unsigned lo0 = (unsigned)__double2loint(L[0]);
    unsigned gh = wave_min_dpp(hi0);
    gh = (unsigned)__builtin_amdgcn_readlane((int)gh, 63);
    unsigned lom = (hi0 == gh) ? lo0 : 0xFFFFFFFFu;
    unsigned gl = wave_min_dpp(lom);
    gl = (unsigned)__builtin_amdgcn_readlane((int)gl, 63);
    bool mine = (hi0 == gh) && (lo0 == gl);   // idx embedded -> unique owner
#pragma unroll
    for (int t = 0; t < LTOP - 1; ++t) L[t] = mine ? L[t + 1] : L[t];
    L[LTOP - 1] = mine ? INF : L[LTOP - 1];
    if (lane == r) { resHi = gh; resLo = gl; }
  }

  if (lane < NNB) {
    float dist = sqrtf(__uint_as_float(resHi));   // hi word IS the f32 |d2| key bits
    nbrD[(size_t)lane * NTOT + P] = dist;         // transposed [NNB][NTOT]
    nbrI[(size_t)lane * NTOT + P] = (int)resLo;   // lo word IS the index
    if (lane == 16) d16[P] = dist;                // dsort[:,16]
  }
}

// ---------------- Kernel C: fused radius + SHOT LRF + log-map + histogram ----------------
// R14 structure (64 distinct points/block, 256 blocks) + register-resident eigh
// (select-network accessors replace the per-lane LDS workspace: each runtime-indexed
// access was an exposed ~100cy LDS round-trip at 0.25 waves/SIMD). Radius: bit-identical
// LDS-staged sequential f32 chain; gathers issued before it so HBM latency hides under.
// hist in LDS (runtime bin index would otherwise force scratch).

__global__ __launch_bounds__(64) void shot_kernel(const float* __restrict__ coords,
                                                  const float* __restrict__ d16,
                                                  const float* __restrict__ nbrD,
                                                  const int* __restrict__ nbrI,
                                                  float* __restrict__ out) {
  __shared__ float buf[NPTS];        // 16 KB: d16 of this block's batch
  __shared__ float hws[25 * 64];     // 6.4 KB: per-lane histogram, stride 64
  int lane = threadIdx.x;
  int g = blockIdx.x * 64 + lane;    // grid exact: 256 blocks x 64
  int b = g >> 12;
  int p = g & (NPTS - 1);
  const float* cb = coords + (size_t)b * NPTS * 3;

  // stage d16 (coalesced)
  for (int i = lane; i < NPTS; i += 64) buf[i] = d16[(size_t)b * NPTS + i];

  // issue all gathers before the radius chain (latency hides under it)
  int jj[NNB];
  float dd[NNB];
#pragma unroll
  for (int k = 0; k < NNB; ++k) {
    jj[k] = nbrI[(size_t)k * NTOT + g];
    dd[k] = nbrD[(size_t)k * NTOT + g];
  }
  float gx[NNB], gy[NNB], gz[NNB];
#pragma unroll
  for (int k = 0; k < NNB; ++k) {
    int j = jj[k];
    gx[k] = cb[j * 3 + 0];
    gy[k] = cb[j * 3 + 1];
    gz[k] = cb[j * 3 + 2];
  }
  float xi = cb[p * 3 + 0], yi = cb[p * 3 + 1], zi = cb[p * 3 + 2];

  __syncthreads();
  // bit-identical sequential f32 radius chain
  float s = 0.0f;
  for (int k = 0; k < NPTS; ++k) s += buf[k];   // same-addr LDS broadcast reads
  float radius = s / 4096.0f;

  float fill = 2.0f * radius / sqrtf(3.0f);

  float nbx[NNB], nby[NNB], nbz[NNB], dk[NNB];
#pragma unroll
  for (int k = 0; k < NNB; ++k) {
    float nx, ny, nz;
    if (dd[k] > radius) { nx = fill; ny = fill; nz = fill; }
    else {
      nx = gx[k] - xi;
      ny = gy[k] - yi;
      nz = gz[k] - zi;
    }
    nbx[k] = nx; nby[k] = ny; nbz[k] = nz;
    dk[k] = sqrtf((nx * nx + ny * ny) + nz * nz);
  }

  float wsum = 0.0f;
  float c00 = 0, c11 = 0, c22 = 0;
  float c01 = 0, c10 = 0, c02 = 0, c20 = 0, c12 = 0, c21 = 0;
  for (int k = 0; k < NNB; ++k) {
    float w = fmaxf(radius - dk[k], 0.0f);
    wsum += w;
    float wx = w * nbx[k], wy = w * nby[k], wz = w * nbz[k];
    c00 += wx * nbx[k]; c01 += wx * nby[k]; c02 += wx * nbz[k];
    c10 += wy * nbx[k]; c11 += wy * nby[k]; c12 += wy * nbz[k];
    c20 += wz * nbx[k]; c21 += wz * nby[k]; c22 += wz * nbz[k];
  }
  float den = wsum + 1e-12f;
  float a00 = c00 / den, a11 = c11 / den, a22 = c22 / den;
  float a01 = c01 / den, a10 = c10 / den;
  float a02 = c02 / den, a20 = c20 / den;
  float a12 = c12 / den, a21 = c21 / den;
  float A10 = 0.5f * (a01 + a10);
  float A20 = 0.5f * (a02 + a20);
  float A21 = 0.5f * (a12 + a21);

  float V[3][3];
  eigh3f_reg(a00, A10, A20, a11, A21, a22, V);

  float xax0 = V[0][2], xax1 = V[1][2], xax2 = V[2][2];
  float zax0 = V[0][0], zax1 = V[1][0], zax2 = V[2][0];

  {
    int pos = 0, neg = 0;
    for (int k = 0; k < NNB; ++k) {
      float dt = (nbx[k] * xax0 + nby[k] * xax1) + nbz[k] * xax2;
      if (dt >= 0.0f) pos++; else neg++;
    }
    if (pos < neg) { xax0 = -xax0; xax1 = -xax1; xax2 = -xax2; }
  }
  {
    int pos = 0, neg = 0;
    for (int k = 0; k < NNB; ++k) {
      float dt = (nbx[k] * zax0 + nby[k] * zax1) + nbz[k] * zax2;
      if (dt >= 0.0f) pos++; else neg++;
    }
    if (pos < neg) { zax0 = -zax0; zax1 = -zax1; zax2 = -zax2; }
  }
  float yax0 = zax1 * xax2 - zax2 * xax1;
  float yax1 = zax2 * xax0 - zax0 * xax2;
  float yax2 = zax0 * xax1 - zax1 * xax0;

  // histogram in LDS (runtime bin index -> scratch if in registers)
  float* hh = &hws[lane];
#pragma unroll
  for (int k = 0; k < NBINS * NBINS; ++k) hh[k * 64] = 0.0f;
  float stp = 2.0f * radius / (float)NBINS;
  for (int k = 0; k < NNB; ++k) {
    float u = (nbx[k] * xax0 + nby[k] * xax1) + nbz[k] * xax2;
    float v = (nbx[k] * yax0 + nby[k] * yax1) + nbz[k] * yax2;
    float pn = sqrtf(u * u + v * v);
    float sc = dk[k] / (pn + 1e-12f);
    float pu = u * sc, pv = v * sc;
    float bxf = floorf((pu + radius) / stp);
    float byf = floorf((pv + radius) / stp);
    if (bxf >= 0.0f && bxf < (float)NBINS && byf >= 0.0f && byf < (float)NBINS) {
      int bx = (int)bxf, by = (int)byf;
      hh[(by * NBINS + bx) * 64] += 1.0f;
    }
  }
  float cvals[NBINS];
#pragma unroll
  for (int i = 0; i < NBINS; ++i) cvals[i] = ((float)i * stp - radius) + 0.5f * stp;
  float nrm2 = 0.0f;
  float hreg[NBINS * NBINS];
#pragma unroll
  for (int i = 0; i < NBINS; ++i) {
#pragma unroll
    for (int j = 0; j < NBINS; ++j) {
      float wgt = radius - sqrtf(cvals[i] * cvals[i] + cvals[j] * cvals[j]);
      float h = hh[(i * NBINS + j) * 64] * wgt;
      hreg[i * NBINS + j] = h;
      nrm2 += h * h;
    }
  }
  float nrm = sqrtf(nrm2);
#pragma unroll
  for (int k = 0; k < NBINS * NBINS; ++k) {
    out[(size_t)g * (NBINS * NBINS) + k] = hreg[k] / nrm;
  }
}

// ---------------- Launch ----------------

extern "C" void kernel_launch(void* const* d_in, const int* in_sizes, int n_in,
                              void* d_out, int out_size, void* d_ws, size_t ws_size,
                              hipStream_t stream) {
  const float* coords = (const float*)d_in[0];
  float* out = (float*)d_out;

  float* wsf = (float*)d_ws;
  float* d16 = wsf + 8;                           // 16384 floats
  float* nbrD = wsf + 8 + (size_t)NTOT;           // [NNB][NTOT] floats
  int* nbrI = (int*)(nbrD + (size_t)NNB * NTOT);  // [NNB][NTOT] ints

  knn_kernel<<<NTOT / 16, 1024, 0, stream>>>(coords, nbrD, nbrI, d16);
  shot_kernel<<<NTOT / 64, 64, 0, stream>>>(coords, d16, nbrD, nbrI, out);
}

// Round 18
// 110.853 us; speedup vs baseline: 1.6174x; 1.0461x over previous
//
#include <hip/hip_runtime.h>
#include <math.h>

// Match XLA/LAPACK f32 rounding: no FMA contraction anywhere in this file.
#pragma clang fp contract(off)

#define NPTS 4096
#define NBATCH 4
#define NTOT (NBATCH * NPTS)
#define NNB 20
#define NBINS 5
#define LTOP 7    // per-lane top-list size; P(lane holds >=8 of top-20) ~ 5e-4 total

// f32 LAPACK machine constants
#define SEPS    5.9604644775390625e-8f   // SLAMCH('E') = 2^-24
#define SSAFMIN 1.17549435e-38f          // SLAMCH('S') = 2^-126

// ---------------- LAPACK helpers (f32, faithful to reference LAPACK >= 3.10) ----------------

__device__ __forceinline__ float f_signf(float a, float b) {
  return __builtin_signbit(b) ? -fabsf(a) : fabsf(a);
}

__device__ float slapy2_(float x, float y) {
  float xa = fabsf(x), ya = fabsf(y);
  float w = fmaxf(xa, ya), z = fminf(xa, ya);
  if (z == 0.0f) return w;
  float t = z / w;
  return w * sqrtf(1.0f + t * t);
}

// LAPACK >= 3.10 slartg (c = |f|/d >= 0, r = sign(f)*d); unscaled path (values are moderate)
__device__ void slartg_(float f, float g, float* c, float* s, float* r) {
  if (g == 0.0f) {
    *c = 1.0f; *s = 0.0f; *r = f;
  } else if (f == 0.0f) {
    *c = 0.0f; *s = __builtin_signbit(g) ? -1.0f : 1.0f; *r = fabsf(g);
  } else {
    float f1 = fabsf(f);
    float d = sqrtf(f * f + g * g);
    *c = f1 / d;
    float rr = __builtin_signbit(f) ? -d : d;
    *r = rr;
    *s = g / rr;
  }
}

__device__ void slaev2_(float a, float b, float c,
                        float* rt1, float* rt2, float* cs1, float* sn1) {
  float sm = a + c;
  float df = a - c;
  float adf = fabsf(df);
  float tb = b + b;
  float ab = fabsf(tb);
  float acmx, acmn;
  if (fabsf(a) > fabsf(c)) { acmx = a; acmn = c; } else { acmx = c; acmn = a; }
  float rt;
  if (adf > ab)      { float t = ab / adf; rt = adf * sqrtf(1.0f + t * t); }
  else if (adf < ab) { float t = adf / ab; rt = ab * sqrtf(1.0f + t * t); }
  else               { rt = ab * sqrtf(2.0f); }
  int sgn1;
  if (sm < 0.0f) {
    *rt1 = 0.5f * (sm - rt); sgn1 = -1;
    *rt2 = (acmx / *rt1) * acmn - (b / *rt1) * b;
  } else if (sm > 0.0f) {
    *rt1 = 0.5f * (sm + rt); sgn1 = 1;
    *rt2 = (acmx / *rt1) * acmn - (b / *rt1) * b;
  } else {
    *rt1 = 0.5f * rt; *rt2 = -0.5f * rt; sgn1 = 1;
  }
  float cs; int sgn2;
  if (df >= 0.0f) { cs = df + rt; sgn2 = 1; }
  else            { cs = df - rt; sgn2 = -1; }
  float acs = fabsf(cs);
  float csv, snv;
  if (acs > ab) {
    float ct = -tb / cs;
    snv = 1.0f / sqrtf(1.0f + ct * ct);
    csv = ct * snv;
  } else {
    if (ab == 0.0f) { csv = 1.0f; snv = 0.0f; }
    else {
      float tn = -cs / tb;
      csv = 1.0f / sqrtf(1.0f + tn * tn);
      snv = tn * csv;
    }
  }
  if (sgn1 == sgn2) { float tn = csv; csv = -snv; snv = tn; }
  *cs1 = csv; *sn1 = snv;
}

// ---- register-resident runtime-index accessors (indices only span {0,1,2}) ----
__device__ __forceinline__ float sel3(float a0, float a1, float a2, int i) {
  float r = (i == 1) ? a1 : a0;
  return (i == 2) ? a2 : r;
}
__device__ __forceinline__ float sel2(float a0, float a1, int i) {
  return (i == 1) ? a1 : a0;
}
#define RD(i)   sel3(d0, d1, d2, (i))
#define RE(i)   sel2(e0, e1, (i))
#define RC(i)   sel2(c0r, c1r, (i))
#define RS(i)   sel2(s0r, s1r, (i))
#define WD(i,v) do{ float _t=(v); int _i=(i); d0=(_i==0)?_t:d0; d1=(_i==1)?_t:d1; d2=(_i==2)?_t:d2; }while(0)
#define WE(i,v) do{ float _t=(v); int _i=(i); e0=(_i==0)?_t:e0; e1=(_i==1)?_t:e1; }while(0)
#define WC(i,v) do{ float _t=(v); int _i=(i); c0r=(_i==0)?_t:c0r; c1r=(_i==1)?_t:c1r; }while(0)
#define WS(i,v) do{ float _t=(v); int _i=(i); s0r=(_i==0)?_t:s0r; s1r=(_i==1)?_t:s1r; }while(0)
// column rotation: t=Z[r][ja]; Z[r][ja]=c*t - s*Z[r][jb]; Z[r][jb]=s*t + c*Z[r][jb]
#define ZROT(ja, jb, cc, ss) do{ int _a=(ja), _b=(jb); float _c=(cc), _s=(ss);                       \
  { float ta=sel3(z00,z01,z02,_a), tb=sel3(z00,z01,z02,_b); float na=_c*ta-_s*tb, nb=_s*ta+_c*tb;   \
    z00=(_a==0)?na:((_b==0)?nb:z00); z01=(_a==1)?na:((_b==1)?nb:z01); z02=(_a==2)?na:((_b==2)?nb:z02);} \
  { float ta=sel3(z10,z11,z12,_a), tb=sel3(z10,z11,z12,_b); float na=_c*ta-_s*tb, nb=_s*ta+_c*tb;   \
    z10=(_a==0)?na:((_b==0)?nb:z10); z11=(_a==1)?na:((_b==1)?nb:z11); z12=(_a==2)?na:((_b==2)?nb:z12);} \
  { float ta=sel3(z20,z21,z22,_a), tb=sel3(z20,z21,z22,_b); float na=_c*ta-_s*tb, nb=_s*ta+_c*tb;   \
    z20=(_a==0)?na:((_b==0)?nb:z20); z21=(_a==1)?na:((_b==1)?nb:z21); z22=(_a==2)?na:((_b==2)?nb:z22);} \
}while(0)
// column swap ia <-> ib
#define ZSWAP(ia, ib) do{ int _a=(ia), _b=(ib);                                                     \
  { float ta=sel3(z00,z01,z02,_a), tb=sel3(z00,z01,z02,_b);                                         \
    z00=(_a==0)?tb:((_b==0)?ta:z00); z01=(_a==1)?tb:((_b==1)?ta:z01); z02=(_a==2)?tb:((_b==2)?ta:z02);} \
  { float ta=sel3(z10,z11,z12,_a), tb=sel3(z10,z11,z12,_b);                                         \
    z10=(_a==0)?tb:((_b==0)?ta:z10); z11=(_a==1)?tb:((_b==1)?ta:z11); z12=(_a==2)?tb:((_b==2)?ta:z12);} \
  { float ta=sel3(z20,z21,z22,_a), tb=sel3(z20,z21,z22,_b);                                         \
    z20=(_a==0)?tb:((_b==0)?ta:z20); z21=(_a==1)?tb:((_b==1)?ta:z21); z22=(_a==2)?tb:((_b==2)?ta:z22);} \
}while(0)

// ssyevd('V','L') for 3x3, fully register-resident (ssytd2 -> ssteqr('I') -> sormtr).
__device__ void eigh3f_reg(float A00, float A10, float A20, float A11, float A21, float A22,
                           float V[3][3]) {
  float taui, v2, beta;
  float alpha = A10;
  float xnorm = fabsf(A20);
  if (xnorm == 0.0f) {
    taui = 0.0f; beta = alpha; v2 = 0.0f;
  } else {
    beta = -f_signf(slapy2_(alpha, xnorm), alpha);
    taui = (beta - alpha) / beta;
    v2 = A20 * (1.0f / (alpha - beta));
  }
  float a11 = A11, a21 = A21, a22 = A22;
  if (taui != 0.0f) {
    float w0 = taui * (a11 + a21 * v2);
    float w1 = taui * (a21 + a22 * v2);
    float al = -0.5f * taui * (w0 + w1 * v2);
    w0 += al; w1 += al * v2;
    a11 -= 2.0f * w0;
    a21 -= (v2 * w0 + w1);
    a22 -= 2.0f * (v2 * w1);
  }
  float d0 = A00, d1 = a11, d2 = a22;
  float e0 = beta, e1 = a21;
  float z00 = 1.0f, z01 = 0.0f, z02 = 0.0f;
  float z10 = 0.0f, z11 = 1.0f, z12 = 0.0f;
  float z20 = 0.0f, z21 = 0.0f, z22 = 1.0f;
  float c0r = 0.0f, c1r = 0.0f, s0r = 0.0f, s1r = 0.0f;

  // ---- SSTEQR('I', n=3) ----
  {
    const int n = 3;
    const float eps = SEPS;
    const float eps2 = SEPS * SEPS;
    const float safmin = SSAFMIN;
    const int nmaxit = 90;
    int jtot = 0;
    int l1 = 1;
    int l = 0, lsv = 0, lend = 0, lendsv = 0, m = 0, mm = 0;
    float p = 0, g = 0, r = 0, c = 0, s = 0, f = 0, bb = 0, rt1 = 0, rt2 = 0;
    float anorm = 0, tst = 0;

L10:
    if (l1 > n) goto L160;
    if (l1 > 1) WE(l1 - 2, 0.0f);
    if (l1 <= n - 1) {
      for (m = l1; m <= n - 1; ++m) {
        tst = fabsf(RE(m - 1));
        if (tst == 0.0f) goto L30;
        if (tst <= (sqrtf(fabsf(RD(m - 1))) * sqrtf(fabsf(RD(m)))) * eps) {
          WE(m - 1, 0.0f);
          goto L30;
        }
      }
    }
    m = n;
L30:
    l = l1; lsv = l; lend = m; lendsv = lend; l1 = m + 1;
    if (lend == l) goto L10;
    anorm = 0.0f;
    for (int i = l; i <= lend; ++i) anorm = fmaxf(anorm, fabsf(RD(i - 1)));
    for (int i = l; i <= lend - 1; ++i) anorm = fmaxf(anorm, fabsf(RE(i - 1)));
    if (anorm == 0.0f) goto L10;
    if (fabsf(RD(lend - 1)) < fabsf(RD(l - 1))) { lend = lsv; l = lendsv; }

    if (lend > l) {
L40:
      if (l != lend) {
        for (m = l; m <= lend - 1; ++m) {
          tst = RE(m - 1) * RE(m - 1);
          if (tst <= (eps2 * fabsf(RD(m - 1))) * fabsf(RD(m)) + safmin) goto L60;
        }
      }
      m = lend;
L60:
      if (m < lend) WE(m - 1, 0.0f);
      p = RD(l - 1);
      if (m == l) goto L80;
      if (m == l + 1) {
        slaev2_(RD(l - 1), RE(l - 1), RD(l), &rt1, &rt2, &c, &s);
        ZROT(l, l - 1, c, s);
        WD(l - 1, rt1); WD(l, rt2); WE(l - 1, 0.0f);
        l += 2;
        if (l <= lend) goto L40;
        goto L140;
      }
      if (jtot == nmaxit) goto L140;
      jtot++;
      g = (RD(l) - p) / (2.0f * RE(l - 1));
      r = slapy2_(g, 1.0f);
      g = RD(m - 1) - p + RE(l - 1) / (g + f_signf(r, g));
      s = 1.0f; c = 1.0f; p = 0.0f;
      for (int i = m - 1; i >= l; --i) {
        f = s * RE(i - 1);
        bb = c * RE(i - 1);
        slartg_(g, f, &c, &s, &r);
        if (i != m - 1) WE(i, r);
        g = RD(i) - p;
        r = (RD(i - 1) - g) * s + 2.0f * c * bb;
        p = s * r;
        WD(i, g + p);
        g = c * r - bb;
        WC(i - 1, c); WS(i - 1, -s);
      }
      mm = m - l + 1;
      for (int j = mm - 1; j >= 1; --j) {
        float ct = RC(l + j - 2), st = RS(l + j - 2);
        ZROT(l + j - 1, l + j - 2, ct, st);
      }
      WD(l - 1, RD(l - 1) - p);
      WE(l - 1, g);
      goto L40;
L80:
      WD(l - 1, p);
      l++;
      if (l <= lend) goto L40;
      goto L140;
    } else {
L90:
      if (l != lend) {
        for (m = l; m >= lend + 1; --m) {
          tst = RE(m - 2) * RE(m - 2);
          if (tst <= (eps2 * fabsf(RD(m - 1))) * fabsf(RD(m - 2)) + safmin) goto L110;
        }
      }
      m = lend;
L110:
      if (m > lend) WE(m - 2, 0.0f);
      p = RD(l - 1);
      if (m == l) goto L130;
      if (m == l - 1) {
        slaev2_(RD(l - 2), RE(l - 2), RD(l - 1), &rt1, &rt2, &c, &s);
        ZROT(l - 1, l - 2, c, s);
        WD(l - 2, rt1); WD(l - 1, rt2); WE(l - 2, 0.0f);
        l -= 2;
        if (l >= lend) goto L90;
        goto L140;
      }
      if (jtot == nmaxit) goto L140;
      jtot++;
      g = (RD(l - 2) - p) / (2.0f * RE(l - 2));
      r = slapy2_(g, 1.0f);
      g = RD(m - 1) - p + RE(l - 2) / (g + f_signf(r, g));
      s = 1.0f; c = 1.0f; p = 0.0f;
      for (int i = m; i <= l - 1; ++i) {
        f = s * RE(i - 1);
        bb = c * RE(i - 1);
        slartg_(g, f, &c, &s, &r);
        if (i != m) WE(i - 2, r);
        g = RD(i - 1) - p;
        r = (RD(i) - g) * s + 2.0f * c * bb;
        p = s * r;
        WD(i - 1, g + p);
        g = c * r - bb;
        WC(i - 1, c); WS(i - 1, s);
      }
      mm = l - m + 1;
      for (int j = 1; j <= mm - 1; ++j) {
        float ct = RC(m + j - 2), st = RS(m + j - 2);
        ZROT(m + j - 1, m + j - 2, ct, st);
      }
      WD(l - 1, RD(l - 1) - p);
      WE(l - 2, g);
      goto L90;
L130:
      WD(l - 1, p);
      l--;
      if (l >= lend) goto L90;
      goto L140;
    }
L140:
    if (jtot < nmaxit) goto L10;
    goto L160;
L160:
    for (int ii = 2; ii <= n; ++ii) {
      int i = ii - 1, k = i;
      float pp = RD(i - 1);
      for (int j = ii; j <= n; ++j)
        if (RD(j - 1) < pp) { k = j; pp = RD(j - 1); }
      if (k != i) {
        WD(k - 1, RD(i - 1));
        WD(i - 1, pp);
        ZSWAP(i - 1, k - 1);
      }
    }
  }

  // ---- sormtr ----
  {
    float t0 = taui * (z10 + v2 * z20);
    float t1 = taui * (z11 + v2 * z21);
    float t2 = taui * (z12 + v2 * z22);
    z10 -= t0; z20 -= t0 * v2;
    z11 -= t1; z21 -= t1 * v2;
    z12 -= t2; z22 -= t2 * v2;
  }
  V[0][0] = z00; V[0][1] = z01; V[0][2] = z02;
  V[1][0] = z10; V[1][1] = z11; V[1][2] = z12;
  V[2][0] = z20; V[2][1] = z21; V[2][2] = z22;
}

// wave64 u32 min-reduce via DPP (row_shr 1/2/4/8 + row_bcast15/31); result valid in lane 63.
__device__ __forceinline__ unsigned wave_min_dpp(unsigned v) {
  unsigned t;
  t = (unsigned)__builtin_amdgcn_update_dpp(-1, (int)v, 0x111, 0xf, 0xf, false); v = t < v ? t : v;
  t = (unsigned)__builtin_amdgcn_update_dpp(-1, (int)v, 0x112, 0xf, 0xf, false); v = t < v ? t : v;
  t = (unsigned)__builtin_amdgcn_update_dpp(-1, (int)v, 0x114, 0xf, 0xf, false); v = t < v ? t : v;
  t = (unsigned)__builtin_amdgcn_update_dpp(-1, (int)v, 0x118, 0xf, 0xf, false); v = t < v ? t : v;
  t = (unsigned)__builtin_amdgcn_update_dpp(-1, (int)v, 0x142, 0xa, 0xf, false); v = t < v ? t : v;
  t = (unsigned)__builtin_amdgcn_update_dpp(-1, (int)v, 0x143, 0xc, 0xf, false); v = t < v ? t : v;
  return v;
}

// ---------------- Kernel A: wave-per-point KNN (FROZEN at R12 best: 72.3 us) ----------------

__global__ __launch_bounds__(1024, 8) void knn_kernel(const float* __restrict__ coords,
                                                      float* __restrict__ nbrD,
                                                      int* __restrict__ nbrI,
                                                      float* __restrict__ d16) {
  __shared__ float4 scs[NPTS];     // 64 KB: {x, y, z, sq}
  int tid = threadIdx.x;
  int wid = tid >> 6;
  int lane = tid & 63;
  int P = blockIdx.x * 16 + wid;   // 16 | 4096, no batch crossing
  int b = P >> 12;
  int p = P & (NPTS - 1);
  const float* cb = coords + (size_t)b * NPTS * 3;

  for (int i = tid; i < NPTS; i += 1024) {
    float x = cb[3 * i + 0], y = cb[3 * i + 1], z = cb[3 * i + 2];
    float sq = (x * x + y * y) + z * z;   // exact ref expression order
    scs[i] = make_float4(x, y, z, sq);
  }
  __syncthreads();

  float4 ci = scs[p];
  float xi = ci.x, yi = ci.y, zi = ci.z, sqi = ci.w;

  const double INF = __hiloint2double(0x7FF00000, 0);   // +inf sentinel (> any composite)
  double L[LTOP];
#pragma unroll
  for (int t = 0; t < LTOP; ++t) L[t] = INF;

#pragma unroll 8
  for (int k = 0; k < NPTS / 64; ++k) {
    int j = k * 64 + lane;
    float4 cj = scs[j];                       // one ds_read_b128
    float dot = (xi * cj.x + yi * cj.y) + zi * cj.z;
    float d2 = (sqi - 2.0f * dot) + cj.w;     // exact ref expression order
    unsigned kb = __float_as_uint(d2) & 0x7FFFFFFFu;   // |d2| bits
    double cur = __hiloint2double((int)kb, j);         // bit-concat composite key
    double m1 = fmax(cur, L[0]);
    double m2 = fmax(cur, L[1]);
    double m3 = fmax(cur, L[2]);
    double m4 = fmax(cur, L[3]);
    double m5 = fmax(cur, L[4]);
    double m6 = fmax(cur, L[5]);
    L[0] = fmin(L[0], cur);
    L[1] = fmin(L[1], m1);
    L[2] = fmin(L[2], m2);
    L[3] = fmin(L[3], m3);
    L[4] = fmin(L[4], m4);
    L[5] = fmin(L[5], m5);
    L[6] = fmin(L[6], m6);
  }

  unsigned resHi = 0, resLo = 0;
  for (int r = 0; r < NNB; ++r) {
    unsigned hi0 = (unsigned)__double2hiint(L[0]);
    unsigned lo0 = (unsigned)__double2loint(L[0]);
    unsigned gh = wave_min_dpp(hi0);
    gh = (unsigned)__builtin_amdgcn_readlane((int)gh, 63);
    unsigned lom = (hi0 == gh) ? lo0 : 0xFFFFFFFFu;
    unsigned gl = wave_min_dpp(lom);
    gl = (unsigned)__builtin_amdgcn_readlane((int)gl, 63);
    bool mine = (hi0 == gh) && (lo0 == gl);   // idx embedded -> unique owner
#pragma unroll
    for (int t = 0; t < LTOP - 1; ++t) L[t] = mine ? L[t + 1] : L[t];
    L[LTOP - 1] = mine ? INF : L[LTOP - 1];
    if (lane == r) { resHi = gh; resLo = gl; }
  }

  if (lane < NNB) {
    float dist = sqrtf(__uint_as_float(resHi));   // hi word IS the f32 |d2| key bits
    nbrD[(size_t)lane * NTOT + P] = dist;         // transposed [NNB][NTOT]
    nbrI[(size_t)lane * NTOT + P] = (int)resLo;   // lo word IS the index
    if (lane == 16) d16[P] = dist;                // dsort[:,16]
  }
}

// ---------------- Kernel C: fused radius + SHOT LRF + log-map + histogram ----------------
// R17 structure + software-pipelined radius chain: the 4096 sequential f32 adds are fed
// by double-buffered ds_read_b128 batches (8 float4 in flight while 32 ordered adds
// retire) -- read schedule changes, ADD ORDER IS IDENTICAL -> bit-exact. The naive
// scalar loop exposed ~19 cyc/element of LDS latency at 0.25 waves/SIMD (~32 us).

__global__ __launch_bounds__(64) void shot_kernel(const float* __restrict__ coords,
                                                  const float* __restrict__ d16,
                                                  const float* __restrict__ nbrD,
                                                  const int* __restrict__ nbrI,
                                                  float* __restrict__ out) {
  __shared__ float buf[NPTS];        // 16 KB: d16 of this block's batch
  __shared__ float hws[25 * 64];     // 6.4 KB: per-lane histogram, stride 64
  int lane = threadIdx.x;
  int g = blockIdx.x * 64 + lane;    // grid exact: 256 blocks x 64
  int b = g >> 12;
  int p = g & (NPTS - 1);
  const float* cb = coords + (size_t)b * NPTS * 3;

  // stage d16 (coalesced)
  for (int i = lane; i < NPTS; i += 64) buf[i] = d16[(size_t)b * NPTS + i];

  // issue all gathers before the radius chain (latency hides under it)
  int jj[NNB];
  float dd[NNB];
#pragma unroll
  for (int k = 0; k < NNB; ++k) {
    jj[k] = nbrI[(size_t)k * NTOT + g];
    dd[k] = nbrD[(size_t)k * NTOT + g];
  }
  float gx[NNB], gy[NNB], gz[NNB];
#pragma unroll
  for (int k = 0; k < NNB; ++k) {
    int j = jj[k];
    gx[k] = cb[j * 3 + 0];
    gy[k] = cb[j * 3 + 1];
    gz[k] = cb[j * 3 + 2];
  }
  float xi = cb[p * 3 + 0], yi = cb[p * 3 + 1], zi = cb[p * 3 + 2];

  __syncthreads();

  // bit-identical sequential f32 radius chain, double-buffered b128 reads.
  // 1024 float4; iteration handles 16 float4 (two batches of 8); adds strictly in order.
  float s = 0.0f;
  {
    const float4* b4 = (const float4*)buf;
    float4 A0, A1, A2, A3, A4, A5, A6, A7;
    float4 B0, B1, B2, B3, B4, B5, B6, B7;
    A0 = b4[0]; A1 = b4[1]; A2 = b4[2]; A3 = b4[3];
    A4 = b4[4]; A5 = b4[5]; A6 = b4[6]; A7 = b4[7];
    for (int blk = 0; blk < 64; ++blk) {
      int base = blk * 16;
      B0 = b4[base + 8];  B1 = b4[base + 9];  B2 = b4[base + 10]; B3 = b4[base + 11];
      B4 = b4[base + 12]; B5 = b4[base + 13]; B6 = b4[base + 14]; B7 = b4[base + 15];
      s += A0.x; s += A0.y; s += A0.z; s += A0.w;
      s += A1.x; s += A1.y; s += A1.z; s += A1.w;
      s += A2.x; s += A2.y; s += A2.z; s += A2.w;
      s += A3.x; s += A3.y; s += A3.z; s += A3.w;
      s += A4.x; s += A4.y; s += A4.z; s += A4.w;
      s += A5.x; s += A5.y; s += A5.z; s += A5.w;
      s += A6.x; s += A6.y; s += A6.z; s += A6.w;
      s += A7.x; s += A7.y; s += A7.z; s += A7.w;
      if (blk < 63) {
        A0 = b4[base + 16]; A1 = b4[base + 17]; A2 = b4[base + 18]; A3 = b4[base + 19];
        A4 = b4[base + 20]; A5 = b4[base + 21]; A6 = b4[base + 22]; A7 = b4[base + 23];
      }
      s += B0.x; s += B0.y; s += B0.z; s += B0.w;
      s += B1.x; s += B1.y; s += B1.z; s += B1.w;
      s += B2.x; s += B2.y; s += B2.z; s += B2.w;
      s += B3.x; s += B3.y; s += B3.z; s += B3.w;
      s += B4.x; s += B4.y; s += B4.z; s += B4.w;
      s += B5.x; s += B5.y; s += B5.z; s += B5.w;
      s += B6.x; s += B6.y; s += B6.z; s += B6.w;
      s += B7.x; s += B7.y; s += B7.z; s += B7.w;
    }
  }
  float radius = s / 4096.0f;

  float fill = 2.0f * radius / sqrtf(3.0f);

  float nbx[NNB], nby[NNB], nbz[NNB], dk[NNB];
#pragma unroll
  for (int k = 0; k < NNB; ++k) {
    float nx, ny, nz;
    if (dd[k] > radius) { nx = fill; ny = fill; nz = fill; }
    else {
      nx = gx[k] - xi;
      ny = gy[k] - yi;
      nz = gz[k] - zi;
    }
    nbx[k] = nx; nby[k] = ny; nbz[k] = nz;
    dk[k] = sqrtf((nx * nx + ny * ny) + nz * nz);
  }

  float wsum = 0.0f;
  float c00 = 0, c11 = 0, c22 = 0;
  float c01 = 0, c10 = 0, c02 = 0, c20 = 0, c12 = 0, c21 = 0;
  for (int k = 0; k < NNB; ++k) {
    float w = fmaxf(radius - dk[k], 0.0f);
    wsum += w;
    float wx = w * nbx[k], wy = w * nby[k], wz = w * nbz[k];
    c00 += wx * nbx[k]; c01 += wx * nby[k]; c02 += wx * nbz[k];
    c10 += wy * nbx[k]; c11 += wy * nby[k]; c12 += wy * nbz[k];
    c20 += wz * nbx[k]; c21 += wz * nby[k]; c22 += wz * nbz[k];
  }
  float den = wsum + 1e-12f;
  float a00 = c00 / den, a11 = c11 / den, a22 = c22 / den;
  float a01 = c01 / den, a10 = c10 / den;
  float a02 = c02 / den, a20 = c20 / den;
  float a12 = c12 / den, a21 = c21 / den;
  float A10 = 0.5f * (a01 + a10);
  float A20 = 0.5f * (a02 + a20);
  float A21 = 0.5f * (a12 + a21);

  float V[3][3];
  eigh3f_reg(a00, A10, A20, a11, A21, a22, V);

  float xax0 = V[0][2], xax1 = V[1][2], xax2 = V[2][2];
  float zax0 = V[0][0], zax1 = V[1][0], zax2 = V[2][0];

  {
    int pos = 0, neg = 0;
    for (int k = 0; k < NNB; ++k) {
      float dt = (nbx[k] * xax0 + nby[k] * xax1) + nbz[k] * xax2;
      if (dt >= 0.0f) pos++; else neg++;
    }
    if (pos < neg) { xax0 = -xax0; xax1 = -xax1; xax2 = -xax2; }
  }
  {
    int pos = 0, neg = 0;
    for (int k = 0; k < NNB; ++k) {
      float dt = (nbx[k] * zax0 + nby[k] * zax1) + nbz[k] * zax2;
      if (dt >= 0.0f) pos++; else neg++;
    }
    if (pos < neg) { zax0 = -zax0; zax1 = -zax1; zax2 = -zax2; }
  }
  float yax0 = zax1 * xax2 - zax2 * xax1;
  float yax1 = zax2 * xax0 - zax0 * xax2;
  float yax2 = zax0 * xax1 - zax1 * xax0;

  // histogram in LDS (runtime bin index -> scratch if in registers)
  float* hh = &hws[lane];
#pragma unroll
  for (int k = 0; k < NBINS * NBINS; ++k) hh[k * 64] = 0.0f;
  float stp = 2.0f * radius / (float)NBINS;
  for (int k = 0; k < NNB; ++k) {
    float u = (nbx[k] * xax0 + nby[k] * xax1) + nbz[k] * xax2;
    float v = (nbx[k] * yax0 + nby[k] * yax1) + nbz[k] * yax2;
    float pn = sqrtf(u * u + v * v);
    float sc = dk[k] / (pn + 1e-12f);
    float pu = u * sc, pv = v * sc;
    float bxf = floorf((pu + radius) / stp);
    float byf = floorf((pv + radius) / stp);
    if (bxf >= 0.0f && bxf < (float)NBINS && byf >= 0.0f && byf < (float)NBINS) {
      int bx = (int)bxf, by = (int)byf;
      hh[(by * NBINS + bx) * 64] += 1.0f;
    }
  }
  float cvals[NBINS];
#pragma unroll
  for (int i = 0; i < NBINS; ++i) cvals[i] = ((float)i * stp - radius) + 0.5f * stp;
  float nrm2 = 0.0f;
  float hreg[NBINS * NBINS];
#pragma unroll
  for (int i = 0; i < NBINS; ++i) {
#pragma unroll
    for (int j = 0; j < NBINS; ++j) {
      float wgt = radius - sqrtf(cvals[i] * cvals[i] + cvals[j] * cvals[j]);
      float h = hh[(i * NBINS + j) * 64] * wgt;
      hreg[i * NBINS + j] = h;
      nrm2 += h * h;
    }
  }
  float nrm = sqrtf(nrm2);
#pragma unroll
  for (int k = 0; k < NBINS * NBINS; ++k) {
    out[(size_t)g * (NBINS * NBINS) + k] = hreg[k] / nrm;
  }
}

// ---------------- Launch ----------------

extern "C" void kernel_launch(void* const* d_in, const int* in_sizes, int n_in,
                              void* d_out, int out_size, void* d_ws, size_t ws_size,
                              hipStream_t stream) {
  const float* coords = (const float*)d_in[0];
  float* out = (float*)d_out;

  float* wsf = (float*)d_ws;
  float* d16 = wsf + 8;                           // 16384 floats
  float* nbrD = wsf + 8 + (size_t)NTOT;           // [NNB][NTOT] floats
  int* nbrI = (int*)(nbrD + (size_t)NNB * NTOT);  // [NNB][NTOT] ints

  knn_kernel<<<NTOT / 16, 1024, 0, stream>>>(coords, nbrD, nbrI, d16);
  shot_kernel<<<NTOT / 64, 64, 0, stream>>>(coords, d16, nbrD, nbrI, out);
}